// Round 2
// baseline (576.998 us; speedup 1.0000x reference)
//
#include <hip/hip_runtime.h>
#include <stdint.h>

typedef unsigned short u16;
typedef __attribute__((ext_vector_type(8))) short short8;
typedef __attribute__((ext_vector_type(4))) float f32x4;

// ---------- bf16 helpers ----------
__device__ __forceinline__ float b2f(u16 x){
  union { unsigned u; float f; } v; v.u = ((unsigned)x) << 16; return v.f;
}
__device__ __forceinline__ float b2fs(short x){ return b2f((u16)x); }
__device__ __forceinline__ u16 f2b(float f){
  union { float f; unsigned u; } v; v.f = f;
  unsigned u = v.u;
  u += 0x7FFFu + ((u >> 16) & 1u);   // round-to-nearest-even
  return (u16)(u >> 16);
}
// dtype-flexible scalar load from a RAW harness input buffer
__device__ __forceinline__ float ldg_f(const void* p, int i, int f32){
  return f32 ? ((const float*)p)[i] : b2f(((const u16*)p)[i]);
}
// async global->LDS 16B (LDS dest must be wave-uniform base + lane*16)
__device__ __forceinline__ void gld16(const void* g, void* l){
  __builtin_amdgcn_global_load_lds(
      (__attribute__((address_space(1))) void*)(g),
      (__attribute__((address_space(3))) void*)(l), 16, 0, 0);
}

// ---------- kernel 0: detect raw input dtype (bf16 vs fp32) ----------
__global__ void detect_dtype(const u16* __restrict__ hid, int* __restrict__ flag){
  if (blockIdx.x == 0){
    int lane = threadIdx.x & 63;
    int plaus = 0;
    for (int i = lane; i < 512; i += 64){
      u16 v = hid[2 * i];
      int e = (v >> 7) & 0xFF;
      if ((e >= 100 && e <= 140) || (v & 0x7FFF) == 0) plaus++;
    }
    #pragma unroll
    for (int xm = 1; xm < 64; xm <<= 1) plaus += __shfl_xor(plaus, xm, 64);
    if (threadIdx.x == 0) *flag = (plaus < 400) ? 1 : 0;
  }
}

// ---------- kernel 1: t = bf16(hidden + pose), 8 elems/thread ----------
__global__ void make_t(const void* __restrict__ hid, const void* __restrict__ pose,
                       u16* __restrict__ t, const int* __restrict__ flag){
  int base = (blockIdx.x * 256 + threadIdx.x) * 8;
  short8 o;
  if (*flag){
    #pragma unroll
    for (int j = 0; j < 2; j++){
      float4 a = *(const float4*)((const float*)hid  + base + j * 4);
      float4 b = *(const float4*)((const float*)pose + base + j * 4);
      o[j * 4 + 0] = (short)f2b(a.x + b.x);
      o[j * 4 + 1] = (short)f2b(a.y + b.y);
      o[j * 4 + 2] = (short)f2b(a.z + b.z);
      o[j * 4 + 3] = (short)f2b(a.w + b.w);
    }
  } else {
    short8 a = *(const short8*)((const u16*)hid  + base);
    short8 b = *(const short8*)((const u16*)pose + base);
    #pragma unroll
    for (int j = 0; j < 8; j++) o[j] = (short)f2b(b2fs(a[j]) + b2fs(b[j]));
  }
  *(short8*)(t + base) = o;
}

// ---------- kernel 2: coalesced transpose + rank-4 LoRA fold ----------
// WT[rowOff+n][k] = sc*(w[k][n] + dn[k][:]·up[:][n]).  64x64 tiles via LDS.
__global__ void prep_w(const void* __restrict__ w, const void* __restrict__ dn,
                       const void* __restrict__ up, u16* __restrict__ WT,
                       int rowOff, float sc, const int* __restrict__ flag)
{
  __shared__ float tile[64][65];            // 65 ≡ 1 mod 32 -> ≤2-way banks
  const int f = *flag;
  const int k0 = blockIdx.x * 64, n0 = blockIdx.y * 64;
  const int tr  = threadIdx.x >> 2;         // 0..63
  const int tc0 = (threadIdx.x & 3) * 16;   // 0,16,32,48
  #pragma unroll
  for (int i = 0; i < 16; i++)
    tile[tr][tc0 + i] = ldg_f(w, (k0 + tr) * 1280 + n0 + tc0 + i, f);
  __syncthreads();
  const int n = n0 + tr;
  float upv[4];
  if (dn){
    #pragma unroll
    for (int r = 0; r < 4; r++) upv[r] = ldg_f(up, r * 1280 + n, f);
  }
  u16 tmp[16];
  #pragma unroll
  for (int i = 0; i < 16; i++){
    int k = k0 + tc0 + i;
    float val = tile[tc0 + i][tr];
    if (dn){
      #pragma unroll
      for (int r = 0; r < 4; r++)
        val += ldg_f(dn, k * 4 + r, f) * upv[r];
    }
    tmp[i] = f2b(val * sc);
  }
  u16* dst = &WT[(rowOff + n) * 1280 + k0 + tc0];
  #pragma unroll
  for (int i = 0; i < 4; i++)
    *(ushort4*)(dst + i * 4) = *(ushort4*)(tmp + i * 4);
}

// ---------- kernel 3: 256x256 8-phase MFMA GEMM (T1+T2+T3+T4+T5) ----------
// C = A @ BT^T. A [M][K] bf16, BT [N][K] bf16. 512 thr = 8 waves (2M x 4N),
// per-wave output 128x64. BK=64, double-buffered LDS (128 KiB) with st_16x32
// swizzle: phys_byte = logical_byte ^ ((logical_byte>>9 & 1) << 5).
// gld16 dest is LINEAR; source address carries the inverse swizzle (involution).
// Schedule per K-tile t (4 phases, 2 barriers each):
//   ph1(kk0,mh0): issue B0(t+1)->buf^1 | ph2(kk0,mh1): issue B1(t+1)
//   ph3(kk1,mh0) | ph4(kk1,mh1)
//   boundary: issue A0,A1(t+2)->buf (post-barrier: all reads of buf done),
//             s_waitcnt vmcnt(4) (t+1 fully staged; t+2's 4 loads in flight),
//             s_barrier.  Never vmcnt(0) mid-loop; every load has >=3 phases lead.
#define GPHASE(KK, MH)                                                         \
  {                                                                            \
    if ((MH) == 0){                                                            \
      _Pragma("unroll")                                                        \
      for (int n = 0; n < 4; n++){                                             \
        int R = wn * 64 + n * 16 + l15;                                        \
        int c = (KK) * 32 + quad * 8;                                          \
        bfr[n] = *(const short8*)&Bsm[b][R * 64 + (c ^ (((R >> 2) & 1) << 4))];\
      }                                                                        \
    }                                                                          \
    short8 af[4];                                                              \
    _Pragma("unroll")                                                          \
    for (int j = 0; j < 4; j++){                                               \
      int R = wm * 128 + ((MH) * 4 + j) * 16 + l15;                            \
      int c = (KK) * 32 + quad * 8;                                            \
      af[j] = *(const short8*)&Asm[b][R * 64 + (c ^ (((R >> 2) & 1) << 4))];   \
    }                                                                          \
    __builtin_amdgcn_s_barrier();                                              \
    asm volatile("s_waitcnt lgkmcnt(0)" ::: "memory");                         \
    __builtin_amdgcn_s_setprio(1);                                             \
    _Pragma("unroll")                                                          \
    for (int j = 0; j < 4; j++)                                                \
      _Pragma("unroll")                                                        \
      for (int n = 0; n < 4; n++)                                              \
        acc[(MH) * 4 + j][n] = __builtin_amdgcn_mfma_f32_16x16x32_bf16(        \
            af[j], bfr[n], acc[(MH) * 4 + j][n], 0, 0, 0);                     \
    __builtin_amdgcn_s_setprio(0);                                             \
    __builtin_amdgcn_s_barrier();                                              \
  }

template<bool BIAS, bool RESID, bool RAWOUT, bool VSPLIT>
__global__ __launch_bounds__(512, 2) void gemm256(
    const u16* __restrict__ A, const u16* __restrict__ BT,
    const void* __restrict__ bias, const void* __restrict__ resid,
    void* __restrict__ Cout, u16* __restrict__ vtg,
    int gridX, int NOUT, int Kdim, const int* __restrict__ flag)
{
  __shared__ alignas(16) u16 Asm[2][256 * 64];   // 64 KiB
  __shared__ alignas(16) u16 Bsm[2][256 * 64];   // 64 KiB
  const int tid  = threadIdx.x;
  const int lane = tid & 63;
  const int w    = tid >> 6;
  const int wm   = w >> 2, wn = w & 3;
  const int quad = lane >> 4, l15 = lane & 15;

  // T1: XCD-aware swizzle (grid % 8 == 0 for all our launches)
  const int nwg = gridDim.x;
  const int id  = blockIdx.x;
  const int swz = (id & 7) * (nwg >> 3) + (id >> 3);
  const int bx  = swz % gridX;
  const int by  = swz / gridX;
  const int tileM = by << 8;
  const int tileN = bx << 8;
  const int f32 = (BIAS || RESID || RAWOUT) ? *flag : 0;

  // stage one half-tile (1024 chunks of 16B): half 0/1 = A rows 0-127/128-255,
  // half 2/3 = B rows 0-127/128-255.  LDS dest linear (chunk p -> p*16);
  // global source slot carries the inverse st_16x32 swizzle.
  auto stageHalf = [&](int bufi, int half, int kt){
    const int k0 = kt << 6;
    #pragma unroll
    for (int s = 0; s < 2; s++){
      int cl  = s * 512 + tid;                 // 0..1023
      int p   = ((half & 1) << 10) + cl;       // phys chunk in tile (0..2047)
      int lc  = p ^ (((p >> 5) & 1) << 1);     // logical chunk (involution)
      int row = lc >> 3, slot = lc & 7;
      if (half < 2)
        gld16(&A [(tileM + row) * Kdim + k0 + slot * 8], (char*)Asm[bufi] + p * 16);
      else
        gld16(&BT[(tileN + row) * Kdim + k0 + slot * 8], (char*)Bsm[bufi] + p * 16);
    }
  };

  f32x4 acc[8][4];
  #pragma unroll
  for (int mi = 0; mi < 8; mi++)
    #pragma unroll
    for (int ni = 0; ni < 4; ni++)
      acc[mi][ni] = (f32x4){0.f, 0.f, 0.f, 0.f};

  const int NT = Kdim >> 6;   // 20 K-tiles (assumes NT >= 2)
  // prologue: tile0 full + tile1 A-halves
  stageHalf(0, 0, 0); stageHalf(0, 1, 0); stageHalf(0, 2, 0); stageHalf(0, 3, 0);
  stageHalf(1, 0, 1); stageHalf(1, 1, 1);
  asm volatile("s_waitcnt vmcnt(4)" ::: "memory");  // tile0 staged; 4 in flight
  __builtin_amdgcn_s_barrier();

  for (int kt = 0; kt < NT; kt++){
    const int b = kt & 1;
    short8 bfr[4];
    // phase 1: kk=0, mh=0  (+ issue B0 of t+1)
    if (kt + 1 < NT) stageHalf(b ^ 1, 2, kt + 1);
    GPHASE(0, 0)
    // phase 2: kk=0, mh=1  (+ issue B1 of t+1)
    if (kt + 1 < NT) stageHalf(b ^ 1, 3, kt + 1);
    GPHASE(0, 1)
    // phase 3: kk=1, mh=0
    GPHASE(1, 0)
    // phase 4: kk=1, mh=1
    GPHASE(1, 1)
    // boundary: buf b fully read by all waves (post final barrier)
    if (kt + 2 < NT){ stageHalf(b, 0, kt + 2); stageHalf(b, 1, kt + 2); }
    if (kt + 1 < NT){
      if (kt + 2 < NT) asm volatile("s_waitcnt vmcnt(4)" ::: "memory");
      else             asm volatile("s_waitcnt vmcnt(0)" ::: "memory");
      __builtin_amdgcn_s_barrier();
    }
  }

  // epilogue: C/D layout col=lane&15, row=quad*4+reg  [m89/m91 verified]
  if (VSPLIT && tileN >= 2560){
    #pragma unroll
    for (int mi = 0; mi < 8; mi++){
      #pragma unroll
      for (int ni = 0; ni < 4; ni++){
        int col = tileN + wn * 64 + ni * 16 + l15;
        int hd = col - 2560;
        int hh = hd / 160;
        int dd = hd - hh * 160;
        int row0 = tileM + wm * 128 + mi * 16 + quad * 4;
        int bb = row0 >> 10;
        long addr = ((long)((bb * 8 + hh) * 160 + dd) << 10) | (long)(row0 & 1023);
        ushort4 pk;
        pk.x = f2b(acc[mi][ni][0]); pk.y = f2b(acc[mi][ni][1]);
        pk.z = f2b(acc[mi][ni][2]); pk.w = f2b(acc[mi][ni][3]);
        *(ushort4*)&vtg[addr] = pk;
      }
    }
  } else {
    #pragma unroll
    for (int mi = 0; mi < 8; mi++){
      #pragma unroll
      for (int ni = 0; ni < 4; ni++){
        int col = tileN + wn * 64 + ni * 16 + l15;
        float bv = 0.f;
        if (BIAS) bv = ldg_f(bias, col, f32);
        #pragma unroll
        for (int r = 0; r < 4; r++){
          int row = tileM + wm * 128 + mi * 16 + quad * 4 + r;
          float v = acc[mi][ni][r] + bv;
          if (RESID) v += ldg_f(resid, row * NOUT + col, f32);
          if (RAWOUT && f32) ((float*)Cout)[row * NOUT + col] = v;
          else               ((u16*)Cout)[row * NOUT + col]   = f2b(v);
        }
      }
    }
  }
}

// ---------- kernel 4: MFMA flash attention (pipelined) ----------
__global__ __launch_bounds__(256, 2) void attn_mfma(
    const u16* __restrict__ qk, const u16* __restrict__ vtg,
    u16* __restrict__ out)
{
  __shared__ alignas(16) u16 Ks[2 * 64 * 160]; // double-buffered K, stride 160
  __shared__ alignas(16) u16 Vt[160 * 64];     // [d][k] linear, XOR-swizzled data
  __shared__ alignas(16) u16 Ps[4 * 32 * 72];  // per-wave P, pad->72

  const int tid  = threadIdx.x, lane = tid & 63, wv = tid >> 6;
  const int quad = lane >> 4,   l15  = lane & 15;
  const int bh = ((blockIdx.y >> 3) << 3) | blockIdx.x;
  const int qt = blockIdx.y & 7;
  const int b  = bh >> 3, h = bh & 7;
  const int rowBase = (b << 10) + (qt << 7);
  const int kBase   = b << 10;

  short8 qa[2][5];
  #pragma unroll
  for (int mi = 0; mi < 2; mi++)
    #pragma unroll
    for (int kk = 0; kk < 5; kk++)
      qa[mi][kk] = *(const short8*)&qk[
          (rowBase + wv * 32 + mi * 16 + l15) * 2560 + h * 160 + kk * 32 + quad * 8];

  f32x4 o[2][10];
  #pragma unroll
  for (int mi = 0; mi < 2; mi++)
    #pragma unroll
    for (int ni = 0; ni < 10; ni++)
      o[mi][ni] = (f32x4){0.f, 0.f, 0.f, 0.f};
  float mr[2][4], lr[2][4];
  #pragma unroll
  for (int mi = 0; mi < 2; mi++)
    #pragma unroll
    for (int r = 0; r < 4; r++){ mr[mi][r] = -1e30f; lr[mi][r] = 0.f; }

  // prologue: stage K tile 0 into Ks[0]
  #pragma unroll
  for (int i = 0; i < 5; i++){
    int c = tid + (i << 8);
    int kr = c / 20, kc = c % 20;
    gld16(&qk[(kBase + kr) * 2560 + 1280 + h * 160 + (kc << 3)],
          (char*)Ks + c * 16);
  }
  __syncthreads();

  int buf = 0;
  for (int kt = 0; kt < 16; kt++){
    // issue V(kt) stage: LDS linear, global source slot pre-swizzled (^ d&7)
    #pragma unroll
    for (int i = 0; i < 5; i++){
      int c = tid + (i << 8);
      int d = c >> 3;
      int l = (c & 7) ^ (d & 7);
      gld16(&vtg[((bh * 160 + d) << 10) + (kt << 6) + (l << 3)],
            (char*)Vt + c * 16);
    }
    // issue K(kt+1) prefetch into other buffer
    if (kt < 15){
      #pragma unroll
      for (int i = 0; i < 5; i++){
        int c = tid + (i << 8);
        int kr = c / 20, kc = c % 20;
        gld16(&qk[(kBase + ((kt + 1) << 6) + kr) * 2560 + 1280 + h * 160 + (kc << 3)],
              (char*)Ks + (buf ^ 1) * 20480 + c * 16);
      }
    }
    const u16* KsR = Ks + buf * 10240;

    f32x4 s[2][4];
    #pragma unroll
    for (int mi = 0; mi < 2; mi++)
      #pragma unroll
      for (int ni = 0; ni < 4; ni++)
        s[mi][ni] = (f32x4){0.f, 0.f, 0.f, 0.f};
    __builtin_amdgcn_s_setprio(1);
    #pragma unroll
    for (int kk = 0; kk < 5; kk++){
      #pragma unroll
      for (int ni = 0; ni < 4; ni++){
        short8 bf = *(const short8*)&KsR[(ni * 16 + l15) * 160 + kk * 32 + quad * 8];
        s[0][ni] = __builtin_amdgcn_mfma_f32_16x16x32_bf16(qa[0][kk], bf, s[0][ni], 0, 0, 0);
        s[1][ni] = __builtin_amdgcn_mfma_f32_16x16x32_bf16(qa[1][kk], bf, s[1][ni], 0, 0, 0);
      }
    }
    __builtin_amdgcn_s_setprio(0);

    float al[2][4];
    #pragma unroll
    for (int mi = 0; mi < 2; mi++){
      #pragma unroll
      for (int r = 0; r < 4; r++){
        float mx = fmaxf(fmaxf(s[mi][0][r], s[mi][1][r]),
                         fmaxf(s[mi][2][r], s[mi][3][r]));
        #pragma unroll
        for (int xm = 1; xm < 16; xm <<= 1) mx = fmaxf(mx, __shfl_xor(mx, xm, 64));
        float mn = fmaxf(mr[mi][r], mx);
        float a  = __expf(mr[mi][r] - mn);
        mr[mi][r] = mn; al[mi][r] = a;
        float sum = 0.f;
        #pragma unroll
        for (int ni = 0; ni < 4; ni++){
          float p = __expf(s[mi][ni][r] - mn);
          s[mi][ni][r] = p; sum += p;
        }
        #pragma unroll
        for (int xm = 1; xm < 16; xm <<= 1) sum += __shfl_xor(sum, xm, 64);
        lr[mi][r] = lr[mi][r] * a + sum;
      }
    }
    #pragma unroll
    for (int mi = 0; mi < 2; mi++)
      #pragma unroll
      for (int ni = 0; ni < 4; ni++)
        #pragma unroll
        for (int r = 0; r < 4; r++)
          Ps[wv * 2304 + (mi * 16 + quad * 4 + r) * 72 + ni * 16 + l15] =
              f2b(s[mi][ni][r]);
    #pragma unroll
    for (int mi = 0; mi < 2; mi++)
      #pragma unroll
      for (int ni = 0; ni < 10; ni++)
        #pragma unroll
        for (int r = 0; r < 4; r++)
          o[mi][ni][r] *= al[mi][r];

    if (kt < 15) asm volatile("s_waitcnt vmcnt(5)" ::: "memory");
    else         asm volatile("s_waitcnt vmcnt(0)" ::: "memory");
    __builtin_amdgcn_s_barrier();

    __builtin_amdgcn_s_setprio(1);
    #pragma unroll
    for (int kk2 = 0; kk2 < 2; kk2++){
      short8 pa0 = *(const short8*)&Ps[wv * 2304 + l15 * 72        + kk2 * 32 + quad * 8];
      short8 pa1 = *(const short8*)&Ps[wv * 2304 + (16 + l15) * 72 + kk2 * 32 + quad * 8];
      #pragma unroll
      for (int ni = 0; ni < 10; ni++){
        short8 vf = *(const short8*)&Vt[((ni * 16 + l15) << 6) +
                                        (((((kk2 << 2) | quad)) ^ (l15 & 7)) << 3)];
        o[0][ni] = __builtin_amdgcn_mfma_f32_16x16x32_bf16(pa0, vf, o[0][ni], 0, 0, 0);
        o[1][ni] = __builtin_amdgcn_mfma_f32_16x16x32_bf16(pa1, vf, o[1][ni], 0, 0, 0);
      }
    }
    __builtin_amdgcn_s_setprio(0);

    asm volatile("s_waitcnt vmcnt(0)" ::: "memory");
    __builtin_amdgcn_s_barrier();
    buf ^= 1;
  }

  #pragma unroll
  for (int mi = 0; mi < 2; mi++){
    #pragma unroll
    for (int r = 0; r < 4; r++){
      float inv = 1.0f / lr[mi][r];
      int row = rowBase + wv * 32 + mi * 16 + quad * 4 + r;
      #pragma unroll
      for (int ni = 0; ni < 10; ni++)
        out[row * 1280 + h * 160 + ni * 16 + l15] = f2b(o[mi][ni][r] * inv);
    }
  }
}

// ---------- launcher ----------
extern "C" void kernel_launch(void* const* d_in, const int* in_sizes, int n_in,
                              void* d_out, int out_size, void* d_ws, size_t ws_size,
                              hipStream_t stream)
{
  const void* hid  = d_in[0];
  const void* pose = d_in[1];
  const void* wm   = d_in[2];
  const void* mb   = d_in[3];
  const void* wq   = d_in[4];
  const void* wk   = d_in[5];
  const void* wv   = d_in[6];
  const void* wo   = d_in[7];
  const void* bo   = d_in[8];
  const void* qd   = d_in[9];
  const void* qu   = d_in[10];
  const void* kd   = d_in[11];
  const void* ku   = d_in[12];
  const void* vd   = d_in[13];
  const void* vu   = d_in[14];
  const void* od   = d_in[15];
  const void* ou   = d_in[16];
  (void)in_sizes; (void)n_in; (void)out_size; (void)ws_size;

  // ws layout (u16 elems), total 46,858,240 u16 + 4B flag = 89.4 MiB
  u16* ws   = (u16*)d_ws;
  u16* qk   = ws;                    // 20,971,520  [8192][2560]
  u16* t    = qk;                    // alias: dead before gemm2 writes qk
  u16* x    = qk + 20971520;         // 10,485,760  [8192][1280]
  u16* vtg  = x + 10485760;          // 10,485,760  [64][160][1024]
  u16* Wbuf = vtg + 10485760;        //  4,915,200  [3840][1280] (reused)
  u16* attnout = x;                  // alias: x dead after gemm2
  int* flag = (int*)(Wbuf + 4915200);

  const float qscale = 0.07905694150420949f;  // 160^-0.5 folded into Wq

  detect_dtype<<<1, 64, 0, stream>>>((const u16*)hid, flag);
  make_t<<<5120, 256, 0, stream>>>(hid, pose, t, flag);
  // x = t @ Wm^T' + mb + hid    (grid 5x32 = 160 blocks, %8==0)
  prep_w<<<dim3(20, 20), 256, 0, stream>>>(wm, nullptr, nullptr, Wbuf, 0, 1.0f, flag);
  gemm256<true, true, false, false><<<160, 512, 0, stream>>>(
      t, Wbuf, mb, hid, x, nullptr, 5, 1280, 1280, flag);
  // qk | vtg = x @ [Wq*s|Wk|Wv]_eff   (grid 15x32 = 480 blocks, %8==0)
  prep_w<<<dim3(20, 20), 256, 0, stream>>>(wq, qd, qu, Wbuf, 0, qscale, flag);
  prep_w<<<dim3(20, 20), 256, 0, stream>>>(wk, kd, ku, Wbuf, 1280, 1.0f, flag);
  prep_w<<<dim3(20, 20), 256, 0, stream>>>(wv, vd, vu, Wbuf, 2560, 1.0f, flag);
  gemm256<false, false, false, true><<<480, 512, 0, stream>>>(
      x, Wbuf, nullptr, nullptr, qk, vtg, 15, 2560, 1280, flag);
  // attention
  attn_mfma<<<dim3(8, 64), 256, 0, stream>>>(qk, vtg, attnout);
  // out = attn @ Wo_eff + bo
  prep_w<<<dim3(20, 20), 256, 0, stream>>>(wo, od, ou, Wbuf, 0, 1.0f, flag);
  gemm256<true, false, true, false><<<160, 512, 0, stream>>>(
      attnout, Wbuf, bo, nullptr, d_out, nullptr, 5, 1280, 1280, flag);
}

// Round 3
// 535.993 us; speedup vs baseline: 1.0765x; 1.0765x over previous
//
#include <hip/hip_runtime.h>
#include <stdint.h>

typedef unsigned short u16;
typedef __attribute__((ext_vector_type(8))) short short8;
typedef __attribute__((ext_vector_type(4))) float f32x4;

// ---------- bf16 helpers ----------
__device__ __forceinline__ float b2f(u16 x){
  union { unsigned u; float f; } v; v.u = ((unsigned)x) << 16; return v.f;
}
__device__ __forceinline__ float b2fs(short x){ return b2f((u16)x); }
__device__ __forceinline__ u16 f2b(float f){
  union { float f; unsigned u; } v; v.f = f;
  unsigned u = v.u;
  u += 0x7FFFu + ((u >> 16) & 1u);   // round-to-nearest-even
  return (u16)(u >> 16);
}
// dtype-flexible scalar load from a RAW harness input buffer
__device__ __forceinline__ float ldg_f(const void* p, int i, int f32){
  return f32 ? ((const float*)p)[i] : b2f(((const u16*)p)[i]);
}
// async global->LDS 16B (LDS dest must be wave-uniform base + lane*16)
__device__ __forceinline__ void gld16(const void* g, void* l){
  __builtin_amdgcn_global_load_lds(
      (__attribute__((address_space(1))) void*)(g),
      (__attribute__((address_space(3))) void*)(l), 16, 0, 0);
}

// ---------- kernel 0: detect raw input dtype (bf16 vs fp32) ----------
__global__ void detect_dtype(const u16* __restrict__ hid, int* __restrict__ flag){
  if (blockIdx.x == 0){
    int lane = threadIdx.x & 63;
    int plaus = 0;
    for (int i = lane; i < 512; i += 64){
      u16 v = hid[2 * i];
      int e = (v >> 7) & 0xFF;
      if ((e >= 100 && e <= 140) || (v & 0x7FFF) == 0) plaus++;
    }
    #pragma unroll
    for (int xm = 1; xm < 64; xm <<= 1) plaus += __shfl_xor(plaus, xm, 64);
    if (threadIdx.x == 0) *flag = (plaus < 400) ? 1 : 0;
  }
}

// ---------- kernel 1: t = bf16(hidden + pose), 8 elems/thread ----------
__global__ void make_t(const void* __restrict__ hid, const void* __restrict__ pose,
                       u16* __restrict__ t, const int* __restrict__ flag){
  int base = (blockIdx.x * 256 + threadIdx.x) * 8;
  short8 o;
  if (*flag){
    #pragma unroll
    for (int j = 0; j < 2; j++){
      float4 a = *(const float4*)((const float*)hid  + base + j * 4);
      float4 b = *(const float4*)((const float*)pose + base + j * 4);
      o[j * 4 + 0] = (short)f2b(a.x + b.x);
      o[j * 4 + 1] = (short)f2b(a.y + b.y);
      o[j * 4 + 2] = (short)f2b(a.z + b.z);
      o[j * 4 + 3] = (short)f2b(a.w + b.w);
    }
  } else {
    short8 a = *(const short8*)((const u16*)hid  + base);
    short8 b = *(const short8*)((const u16*)pose + base);
    #pragma unroll
    for (int j = 0; j < 8; j++) o[j] = (short)f2b(b2fs(a[j]) + b2fs(b[j]));
  }
  *(short8*)(t + base) = o;
}

// ---------- kernel 2: coalesced transpose + rank-4 LoRA fold ----------
// WT[rowOff+n][k] = sc*(w[k][n] + dn[k][:]·up[:][n]).  64x64 tiles via LDS.
__global__ void prep_w(const void* __restrict__ w, const void* __restrict__ dn,
                       const void* __restrict__ up, u16* __restrict__ WT,
                       int rowOff, float sc, const int* __restrict__ flag)
{
  __shared__ float tile[64][65];            // 65 ≡ 1 mod 32 -> ≤2-way banks
  const int f = *flag;
  const int k0 = blockIdx.x * 64, n0 = blockIdx.y * 64;
  const int tr  = threadIdx.x >> 2;         // 0..63
  const int tc0 = (threadIdx.x & 3) * 16;   // 0,16,32,48
  #pragma unroll
  for (int i = 0; i < 16; i++)
    tile[tr][tc0 + i] = ldg_f(w, (k0 + tr) * 1280 + n0 + tc0 + i, f);
  __syncthreads();
  const int n = n0 + tr;
  float upv[4];
  if (dn){
    #pragma unroll
    for (int r = 0; r < 4; r++) upv[r] = ldg_f(up, r * 1280 + n, f);
  }
  u16 tmp[16];
  #pragma unroll
  for (int i = 0; i < 16; i++){
    int k = k0 + tc0 + i;
    float val = tile[tc0 + i][tr];
    if (dn){
      #pragma unroll
      for (int r = 0; r < 4; r++)
        val += ldg_f(dn, k * 4 + r, f) * upv[r];
    }
    tmp[i] = f2b(val * sc);
  }
  u16* dst = &WT[(rowOff + n) * 1280 + k0 + tc0];
  #pragma unroll
  for (int i = 0; i < 4; i++)
    *(ushort4*)(dst + i * 4) = *(ushort4*)(tmp + i * 4);
}

// ---------- kernel 3a: 128x128 m97-structure GEMM (for N=1280 shapes) ----------
// 640 blocks fill the chip; 256² template would give only 160 blocks here.
template<bool BIAS, bool RESID, bool RAWOUT>
__global__ __launch_bounds__(256) void gemm_bt(
    const u16* __restrict__ A, const u16* __restrict__ BT,
    const void* __restrict__ bias, const void* __restrict__ resid,
    void* __restrict__ Cout, int NOUT, int Kdim, const int* __restrict__ flag)
{
  __shared__ alignas(16) u16 As[128 * 32];
  __shared__ alignas(16) u16 Bs[128 * 32];
  const int tid  = threadIdx.x;
  const int lane = tid & 63;
  const int w    = tid >> 6;
  const int wm   = w >> 1, wn = w & 1;
  const int quad = lane >> 4, l15 = lane & 15;
  const int tileM = blockIdx.y << 7;
  const int tileN = blockIdx.x << 7;
  const int f32 = (BIAS || RESID || RAWOUT) ? *flag : 0;

  f32x4 acc[4][4];
  #pragma unroll
  for (int mi = 0; mi < 4; mi++)
    #pragma unroll
    for (int ni = 0; ni < 4; ni++)
      acc[mi][ni] = (f32x4){0.f, 0.f, 0.f, 0.f};

  for (int k0 = 0; k0 < Kdim; k0 += 32){
    {
      int c = tid;
      gld16(&A [(tileM + (c >> 2)) * Kdim + k0 + ((c & 3) << 3)], (char*)As + c * 16);
      gld16(&BT[(tileN + (c >> 2)) * Kdim + k0 + ((c & 3) << 3)], (char*)Bs + c * 16);
      c = tid + 256;
      gld16(&A [(tileM + (c >> 2)) * Kdim + k0 + ((c & 3) << 3)], (char*)As + c * 16);
      gld16(&BT[(tileN + (c >> 2)) * Kdim + k0 + ((c & 3) << 3)], (char*)Bs + c * 16);
    }
    __syncthreads();

    short8 af[4], bfr[4];
    #pragma unroll
    for (int mi = 0; mi < 4; mi++)
      af[mi] = *(const short8*)(As + (wm * 64 + mi * 16 + l15) * 32 + quad * 8);
    #pragma unroll
    for (int ni = 0; ni < 4; ni++)
      bfr[ni] = *(const short8*)(Bs + (wn * 64 + ni * 16 + l15) * 32 + quad * 8);
    #pragma unroll
    for (int mi = 0; mi < 4; mi++)
      #pragma unroll
      for (int ni = 0; ni < 4; ni++)
        acc[mi][ni] = __builtin_amdgcn_mfma_f32_16x16x32_bf16(
            af[mi], bfr[ni], acc[mi][ni], 0, 0, 0);
    __syncthreads();
  }

  #pragma unroll
  for (int mi = 0; mi < 4; mi++){
    #pragma unroll
    for (int ni = 0; ni < 4; ni++){
      int col = tileN + wn * 64 + ni * 16 + l15;
      float bv = 0.f;
      if (BIAS) bv = ldg_f(bias, col, f32);
      #pragma unroll
      for (int r = 0; r < 4; r++){
        int row = tileM + wm * 64 + mi * 16 + quad * 4 + r;
        float v = acc[mi][ni][r] + bv;
        if (RESID) v += ldg_f(resid, row * NOUT + col, f32);
        if (RAWOUT && f32) ((float*)Cout)[row * NOUT + col] = v;
        else               ((u16*)Cout)[row * NOUT + col]   = f2b(v);
      }
    }
  }
}

// ---------- kernel 3b: 256x256 8-phase MFMA GEMM (QKV projection) ----------
// C = A @ BT^T. 512 thr = 8 waves (2M x 4N), per-wave output 128x64. BK=64,
// double-buffered LDS (128 KiB). Swizzle: each LDS row = 8 x 16B slots;
// phys_slot = logical_slot ^ (row & 7)  -> 16 same-col lanes spread across all
// 8 slots = conflict-free ds_read_b128.  gld16 dest stays LINEAR; the global
// SOURCE address carries the same XOR (involution per row) [rule #21].
// Schedule per K-tile t: 4 phases {ds_read -> barrier -> lgkm(0) -> 16 MFMA
// (setprio) -> barrier}; B(t+1) issued at phases 1-2, A(t+2) at boundary;
// boundary wait = vmcnt(4) (t+1 staged, t+2's A in flight). Never vmcnt(0).
#define GPHASE(KK, MH)                                                         \
  {                                                                            \
    if ((MH) == 0){                                                            \
      _Pragma("unroll")                                                        \
      for (int n = 0; n < 4; n++){                                             \
        int R = wn * 64 + n * 16 + l15;                                        \
        int sl = (KK) * 4 + quad;                                              \
        bfr[n] = *(const short8*)&Bsm[b][R * 64 + ((sl ^ (R & 7)) << 3)];      \
      }                                                                        \
    }                                                                          \
    short8 af[4];                                                              \
    _Pragma("unroll")                                                          \
    for (int j = 0; j < 4; j++){                                               \
      int R = wm * 128 + ((MH) * 4 + j) * 16 + l15;                            \
      int sl = (KK) * 4 + quad;                                                \
      af[j] = *(const short8*)&Asm[b][R * 64 + ((sl ^ (R & 7)) << 3)];         \
    }                                                                          \
    __builtin_amdgcn_s_barrier();                                              \
    asm volatile("s_waitcnt lgkmcnt(0)" ::: "memory");                         \
    __builtin_amdgcn_s_setprio(1);                                             \
    _Pragma("unroll")                                                          \
    for (int j = 0; j < 4; j++)                                                \
      _Pragma("unroll")                                                        \
      for (int n = 0; n < 4; n++)                                              \
        acc[(MH) * 4 + j][n] = __builtin_amdgcn_mfma_f32_16x16x32_bf16(        \
            af[j], bfr[n], acc[(MH) * 4 + j][n], 0, 0, 0);                     \
    __builtin_amdgcn_s_setprio(0);                                             \
    __builtin_amdgcn_s_barrier();                                              \
  }

__global__ __launch_bounds__(512, 2) void gemm256_qkv(
    const u16* __restrict__ A, const u16* __restrict__ BT,
    u16* __restrict__ Cout, u16* __restrict__ vtg,
    int gridX, int Kdim)
{
  __shared__ alignas(16) u16 Asm[2][256 * 64];   // 64 KiB
  __shared__ alignas(16) u16 Bsm[2][256 * 64];   // 64 KiB
  const int tid  = threadIdx.x;
  const int lane = tid & 63;
  const int w    = tid >> 6;
  const int wm   = w >> 2, wn = w & 3;
  const int quad = lane >> 4, l15 = lane & 15;

  // T1: XCD-aware swizzle (grid % 8 == 0)
  const int nwg = gridDim.x;
  const int id  = blockIdx.x;
  const int swz = (id & 7) * (nwg >> 3) + (id >> 3);
  const int bx  = swz % gridX;
  const int by  = swz / gridX;
  const int tileM = by << 8;
  const int tileN = bx << 8;

  // stage one half-tile (1024 chunks of 16B): half 0/1 = A rows 0-127/128-255,
  // half 2/3 = B rows 0-127/128-255.  LDS dest linear (chunk p -> p*16);
  // global source slot = phys_slot ^ (row&7) (inverse swizzle).
  auto stageHalf = [&](int bufi, int half, int kt){
    const int k0 = kt << 6;
    #pragma unroll
    for (int s = 0; s < 2; s++){
      int cl   = s * 512 + tid;                 // 0..1023
      int p    = ((half & 1) << 10) + cl;       // phys chunk in tile (0..2047)
      int row  = p >> 3;
      int lslt = (p & 7) ^ (row & 7);           // logical 16B slot
      if (half < 2)
        gld16(&A [(tileM + row) * Kdim + k0 + lslt * 8], (char*)Asm[bufi] + p * 16);
      else
        gld16(&BT[(tileN + row) * Kdim + k0 + lslt * 8], (char*)Bsm[bufi] + p * 16);
    }
  };

  f32x4 acc[8][4];
  #pragma unroll
  for (int mi = 0; mi < 8; mi++)
    #pragma unroll
    for (int ni = 0; ni < 4; ni++)
      acc[mi][ni] = (f32x4){0.f, 0.f, 0.f, 0.f};

  const int NT = Kdim >> 6;   // 20 K-tiles
  stageHalf(0, 0, 0); stageHalf(0, 1, 0); stageHalf(0, 2, 0); stageHalf(0, 3, 0);
  stageHalf(1, 0, 1); stageHalf(1, 1, 1);
  asm volatile("s_waitcnt vmcnt(4)" ::: "memory");  // tile0 staged; 4 in flight
  __builtin_amdgcn_s_barrier();

  for (int kt = 0; kt < NT; kt++){
    const int b = kt & 1;
    short8 bfr[4];
    if (kt + 1 < NT) stageHalf(b ^ 1, 2, kt + 1);
    GPHASE(0, 0)
    if (kt + 1 < NT) stageHalf(b ^ 1, 3, kt + 1);
    GPHASE(0, 1)
    GPHASE(1, 0)
    GPHASE(1, 1)
    if (kt + 2 < NT){ stageHalf(b, 0, kt + 2); stageHalf(b, 1, kt + 2); }
    if (kt + 1 < NT){
      if (kt + 2 < NT) asm volatile("s_waitcnt vmcnt(4)" ::: "memory");
      else             asm volatile("s_waitcnt vmcnt(0)" ::: "memory");
      __builtin_amdgcn_s_barrier();
    }
  }

  // epilogue: C/D layout col=lane&15, row=quad*4+reg  [m89/m91 verified]
  if (tileN >= 2560){
    #pragma unroll
    for (int mi = 0; mi < 8; mi++){
      #pragma unroll
      for (int ni = 0; ni < 4; ni++){
        int col = tileN + wn * 64 + ni * 16 + l15;
        int hd = col - 2560;
        int hh = hd / 160;
        int dd = hd - hh * 160;
        int row0 = tileM + wm * 128 + mi * 16 + quad * 4;
        int bb = row0 >> 10;
        long addr = ((long)((bb * 8 + hh) * 160 + dd) << 10) | (long)(row0 & 1023);
        ushort4 pk;
        pk.x = f2b(acc[mi][ni][0]); pk.y = f2b(acc[mi][ni][1]);
        pk.z = f2b(acc[mi][ni][2]); pk.w = f2b(acc[mi][ni][3]);
        *(ushort4*)&vtg[addr] = pk;
      }
    }
  } else {
    #pragma unroll
    for (int mi = 0; mi < 8; mi++){
      #pragma unroll
      for (int ni = 0; ni < 4; ni++){
        int col = tileN + wn * 64 + ni * 16 + l15;
        #pragma unroll
        for (int r = 0; r < 4; r++){
          int row = tileM + wm * 128 + mi * 16 + quad * 4 + r;
          Cout[row * 2560 + col] = f2b(acc[mi][ni][r]);
        }
      }
    }
  }
}

// ---------- kernel 4: MFMA flash attention (pipelined) ----------
__global__ __launch_bounds__(256, 2) void attn_mfma(
    const u16* __restrict__ qk, const u16* __restrict__ vtg,
    u16* __restrict__ out)
{
  __shared__ alignas(16) u16 Ks[2 * 64 * 160]; // double-buffered K, stride 160
  __shared__ alignas(16) u16 Vt[160 * 64];     // [d][k] linear, XOR-swizzled data
  __shared__ alignas(16) u16 Ps[4 * 32 * 72];  // per-wave P, pad->72

  const int tid  = threadIdx.x, lane = tid & 63, wv = tid >> 6;
  const int quad = lane >> 4,   l15  = lane & 15;
  const int bh = ((blockIdx.y >> 3) << 3) | blockIdx.x;
  const int qt = blockIdx.y & 7;
  const int b  = bh >> 3, h = bh & 7;
  const int rowBase = (b << 10) + (qt << 7);
  const int kBase   = b << 10;

  short8 qa[2][5];
  #pragma unroll
  for (int mi = 0; mi < 2; mi++)
    #pragma unroll
    for (int kk = 0; kk < 5; kk++)
      qa[mi][kk] = *(const short8*)&qk[
          (rowBase + wv * 32 + mi * 16 + l15) * 2560 + h * 160 + kk * 32 + quad * 8];

  f32x4 o[2][10];
  #pragma unroll
  for (int mi = 0; mi < 2; mi++)
    #pragma unroll
    for (int ni = 0; ni < 10; ni++)
      o[mi][ni] = (f32x4){0.f, 0.f, 0.f, 0.f};
  float mr[2][4], lr[2][4];
  #pragma unroll
  for (int mi = 0; mi < 2; mi++)
    #pragma unroll
    for (int r = 0; r < 4; r++){ mr[mi][r] = -1e30f; lr[mi][r] = 0.f; }

  #pragma unroll
  for (int i = 0; i < 5; i++){
    int c = tid + (i << 8);
    int kr = c / 20, kc = c % 20;
    gld16(&qk[(kBase + kr) * 2560 + 1280 + h * 160 + (kc << 3)],
          (char*)Ks + c * 16);
  }
  __syncthreads();

  int buf = 0;
  for (int kt = 0; kt < 16; kt++){
    #pragma unroll
    for (int i = 0; i < 5; i++){
      int c = tid + (i << 8);
      int d = c >> 3;
      int l = (c & 7) ^ (d & 7);
      gld16(&vtg[((bh * 160 + d) << 10) + (kt << 6) + (l << 3)],
            (char*)Vt + c * 16);
    }
    if (kt < 15){
      #pragma unroll
      for (int i = 0; i < 5; i++){
        int c = tid + (i << 8);
        int kr = c / 20, kc = c % 20;
        gld16(&qk[(kBase + ((kt + 1) << 6) + kr) * 2560 + 1280 + h * 160 + (kc << 3)],
              (char*)Ks + (buf ^ 1) * 20480 + c * 16);
      }
    }
    const u16* KsR = Ks + buf * 10240;

    f32x4 s[2][4];
    #pragma unroll
    for (int mi = 0; mi < 2; mi++)
      #pragma unroll
      for (int ni = 0; ni < 4; ni++)
        s[mi][ni] = (f32x4){0.f, 0.f, 0.f, 0.f};
    __builtin_amdgcn_s_setprio(1);
    #pragma unroll
    for (int kk = 0; kk < 5; kk++){
      #pragma unroll
      for (int ni = 0; ni < 4; ni++){
        short8 bf = *(const short8*)&KsR[(ni * 16 + l15) * 160 + kk * 32 + quad * 8];
        s[0][ni] = __builtin_amdgcn_mfma_f32_16x16x32_bf16(qa[0][kk], bf, s[0][ni], 0, 0, 0);
        s[1][ni] = __builtin_amdgcn_mfma_f32_16x16x32_bf16(qa[1][kk], bf, s[1][ni], 0, 0, 0);
      }
    }
    __builtin_amdgcn_s_setprio(0);

    float al[2][4];
    #pragma unroll
    for (int mi = 0; mi < 2; mi++){
      #pragma unroll
      for (int r = 0; r < 4; r++){
        float mx = fmaxf(fmaxf(s[mi][0][r], s[mi][1][r]),
                         fmaxf(s[mi][2][r], s[mi][3][r]));
        #pragma unroll
        for (int xm = 1; xm < 16; xm <<= 1) mx = fmaxf(mx, __shfl_xor(mx, xm, 64));
        float mn = fmaxf(mr[mi][r], mx);
        float a  = __expf(mr[mi][r] - mn);
        mr[mi][r] = mn; al[mi][r] = a;
        float sum = 0.f;
        #pragma unroll
        for (int ni = 0; ni < 4; ni++){
          float p = __expf(s[mi][ni][r] - mn);
          s[mi][ni][r] = p; sum += p;
        }
        #pragma unroll
        for (int xm = 1; xm < 16; xm <<= 1) sum += __shfl_xor(sum, xm, 64);
        lr[mi][r] = lr[mi][r] * a + sum;
      }
    }
    #pragma unroll
    for (int mi = 0; mi < 2; mi++)
      #pragma unroll
      for (int ni = 0; ni < 4; ni++)
        #pragma unroll
        for (int r = 0; r < 4; r++)
          Ps[wv * 2304 + (mi * 16 + quad * 4 + r) * 72 + ni * 16 + l15] =
              f2b(s[mi][ni][r]);
    #pragma unroll
    for (int mi = 0; mi < 2; mi++)
      #pragma unroll
      for (int ni = 0; ni < 10; ni++)
        #pragma unroll
        for (int r = 0; r < 4; r++)
          o[mi][ni][r] *= al[mi][r];

    if (kt < 15) asm volatile("s_waitcnt vmcnt(5)" ::: "memory");
    else         asm volatile("s_waitcnt vmcnt(0)" ::: "memory");
    __builtin_amdgcn_s_barrier();

    __builtin_amdgcn_s_setprio(1);
    #pragma unroll
    for (int kk2 = 0; kk2 < 2; kk2++){
      short8 pa0 = *(const short8*)&Ps[wv * 2304 + l15 * 72        + kk2 * 32 + quad * 8];
      short8 pa1 = *(const short8*)&Ps[wv * 2304 + (16 + l15) * 72 + kk2 * 32 + quad * 8];
      #pragma unroll
      for (int ni = 0; ni < 10; ni++){
        short8 vf = *(const short8*)&Vt[((ni * 16 + l15) << 6) +
                                        (((((kk2 << 2) | quad)) ^ (l15 & 7)) << 3)];
        o[0][ni] = __builtin_amdgcn_mfma_f32_16x16x32_bf16(pa0, vf, o[0][ni], 0, 0, 0);
        o[1][ni] = __builtin_amdgcn_mfma_f32_16x16x32_bf16(pa1, vf, o[1][ni], 0, 0, 0);
      }
    }
    __builtin_amdgcn_s_setprio(0);

    asm volatile("s_waitcnt vmcnt(0)" ::: "memory");
    __builtin_amdgcn_s_barrier();
    buf ^= 1;
  }

  #pragma unroll
  for (int mi = 0; mi < 2; mi++){
    #pragma unroll
    for (int r = 0; r < 4; r++){
      float inv = 1.0f / lr[mi][r];
      int row = rowBase + wv * 32 + mi * 16 + quad * 4 + r;
      #pragma unroll
      for (int ni = 0; ni < 10; ni++)
        out[row * 1280 + h * 160 + ni * 16 + l15] = f2b(o[mi][ni][r] * inv);
    }
  }
}

// ---------- launcher ----------
extern "C" void kernel_launch(void* const* d_in, const int* in_sizes, int n_in,
                              void* d_out, int out_size, void* d_ws, size_t ws_size,
                              hipStream_t stream)
{
  const void* hid  = d_in[0];
  const void* pose = d_in[1];
  const void* wm   = d_in[2];
  const void* mb   = d_in[3];
  const void* wq   = d_in[4];
  const void* wk   = d_in[5];
  const void* wv   = d_in[6];
  const void* wo   = d_in[7];
  const void* bo   = d_in[8];
  const void* qd   = d_in[9];
  const void* qu   = d_in[10];
  const void* kd   = d_in[11];
  const void* ku   = d_in[12];
  const void* vd   = d_in[13];
  const void* vu   = d_in[14];
  const void* od   = d_in[15];
  const void* ou   = d_in[16];
  (void)in_sizes; (void)n_in; (void)out_size; (void)ws_size;

  // ws layout (u16 elems), total 46,858,240 u16 + 4B flag = 89.4 MiB
  u16* ws   = (u16*)d_ws;
  u16* qk   = ws;                    // 20,971,520  [8192][2560]
  u16* t    = qk;                    // alias: dead before gemm2 writes qk
  u16* x    = qk + 20971520;         // 10,485,760  [8192][1280]
  u16* vtg  = x + 10485760;          // 10,485,760  [64][160][1024]
  u16* Wbuf = vtg + 10485760;        //  4,915,200  [3840][1280] (reused)
  u16* attnout = x;                  // alias: x dead after gemm2
  int* flag = (int*)(Wbuf + 4915200);

  const float qscale = 0.07905694150420949f;  // 160^-0.5 folded into Wq

  detect_dtype<<<1, 64, 0, stream>>>((const u16*)hid, flag);
  make_t<<<5120, 256, 0, stream>>>(hid, pose, t, flag);
  // x = t @ Wm^T' + mb + hid   (128² structure: 640 blocks fill the chip)
  prep_w<<<dim3(20, 20), 256, 0, stream>>>(wm, nullptr, nullptr, Wbuf, 0, 1.0f, flag);
  gemm_bt<true, true, false><<<dim3(10, 64), 256, 0, stream>>>(
      t, Wbuf, mb, hid, x, 1280, 1280, flag);
  // qk | vtg = x @ [Wq*s|Wk|Wv]_eff   (256² 8-phase: 480 blocks, %8==0)
  prep_w<<<dim3(20, 20), 256, 0, stream>>>(wq, qd, qu, Wbuf, 0, qscale, flag);
  prep_w<<<dim3(20, 20), 256, 0, stream>>>(wk, kd, ku, Wbuf, 1280, 1.0f, flag);
  prep_w<<<dim3(20, 20), 256, 0, stream>>>(wv, vd, vu, Wbuf, 2560, 1.0f, flag);
  gemm256_qkv<<<480, 512, 0, stream>>>(x, Wbuf, qk, vtg, 15, 1280);
  // attention
  attn_mfma<<<dim3(8, 64), 256, 0, stream>>>(qk, vtg, attnout);
  // out = attn @ Wo_eff + bo   (128² structure)
  prep_w<<<dim3(20, 20), 256, 0, stream>>>(wo, od, ou, Wbuf, 0, 1.0f, flag);
  gemm_bt<true, false, true><<<dim3(10, 64), 256, 0, stream>>>(
      attnout, Wbuf, bo, nullptr, d_out, 1280, 1280, flag);
}

// Round 4
// 509.111 us; speedup vs baseline: 1.1333x; 1.0528x over previous
//
#include <hip/hip_runtime.h>
#include <stdint.h>

typedef unsigned short u16;
typedef __attribute__((ext_vector_type(8))) short short8;
typedef __attribute__((ext_vector_type(4))) float f32x4;

// ---------- bf16 helpers ----------
__device__ __forceinline__ float b2f(u16 x){
  union { unsigned u; float f; } v; v.u = ((unsigned)x) << 16; return v.f;
}
__device__ __forceinline__ float b2fs(short x){ return b2f((u16)x); }
__device__ __forceinline__ u16 f2b(float f){
  union { float f; unsigned u; } v; v.f = f;
  unsigned u = v.u;
  u += 0x7FFFu + ((u >> 16) & 1u);   // round-to-nearest-even
  return (u16)(u >> 16);
}
// dtype-flexible scalar load from a RAW harness input buffer
__device__ __forceinline__ float ldg_f(const void* p, int i, int f32){
  return f32 ? ((const float*)p)[i] : b2f(((const u16*)p)[i]);
}
// async global->LDS 16B (LDS dest must be wave-uniform base + lane*16)
__device__ __forceinline__ void gld16(const void* g, void* l){
  __builtin_amdgcn_global_load_lds(
      (__attribute__((address_space(1))) void*)(g),
      (__attribute__((address_space(3))) void*)(l), 16, 0, 0);
}
// 32-bit LDS byte offset of a __shared__ object (for inline-asm ds_read)
__device__ __forceinline__ unsigned lds_addr(const void* p){
  return (unsigned)(size_t)(__attribute__((address_space(3))) const void*)p;
}
// inline-asm ds_read_b128: compiler cannot alias-connect this to the
// global_load_lds writes, so it emits NO conservative vmcnt before it.
// Ordering is enforced by our own lgkmcnt(0)+sched_barrier(0) [rule #18].
__device__ __forceinline__ short8 ds_r128(unsigned addr){
  short8 r;
  asm volatile("ds_read_b128 %0, %1" : "=v"(r) : "v"(addr));
  return r;
}

// ---------- kernel 0: detect raw input dtype (bf16 vs fp32) ----------
__global__ void detect_dtype(const u16* __restrict__ hid, int* __restrict__ flag){
  if (blockIdx.x == 0){
    int lane = threadIdx.x & 63;
    int plaus = 0;
    for (int i = lane; i < 512; i += 64){
      u16 v = hid[2 * i];
      int e = (v >> 7) & 0xFF;
      if ((e >= 100 && e <= 140) || (v & 0x7FFF) == 0) plaus++;
    }
    #pragma unroll
    for (int xm = 1; xm < 64; xm <<= 1) plaus += __shfl_xor(plaus, xm, 64);
    if (threadIdx.x == 0) *flag = (plaus < 400) ? 1 : 0;
  }
}

// ---------- kernel 1: t = bf16(hidden + pose), 8 elems/thread ----------
__global__ void make_t(const void* __restrict__ hid, const void* __restrict__ pose,
                       u16* __restrict__ t, const int* __restrict__ flag){
  int base = (blockIdx.x * 256 + threadIdx.x) * 8;
  short8 o;
  if (*flag){
    #pragma unroll
    for (int j = 0; j < 2; j++){
      float4 a = *(const float4*)((const float*)hid  + base + j * 4);
      float4 b = *(const float4*)((const float*)pose + base + j * 4);
      o[j * 4 + 0] = (short)f2b(a.x + b.x);
      o[j * 4 + 1] = (short)f2b(a.y + b.y);
      o[j * 4 + 2] = (short)f2b(a.z + b.z);
      o[j * 4 + 3] = (short)f2b(a.w + b.w);
    }
  } else {
    short8 a = *(const short8*)((const u16*)hid  + base);
    short8 b = *(const short8*)((const u16*)pose + base);
    #pragma unroll
    for (int j = 0; j < 8; j++) o[j] = (short)f2b(b2fs(a[j]) + b2fs(b[j]));
  }
  *(short8*)(t + base) = o;
}

// ---------- kernel 2: coalesced transpose + rank-4 LoRA fold ----------
// WT[rowOff+n][k] = sc*(w[k][n] + dn[k][:]·up[:][n]).  64x64 tiles via LDS.
__global__ void prep_w(const void* __restrict__ w, const void* __restrict__ dn,
                       const void* __restrict__ up, u16* __restrict__ WT,
                       int rowOff, float sc, const int* __restrict__ flag)
{
  __shared__ float tile[64][65];            // 65 ≡ 1 mod 32 -> ≤2-way banks
  const int f = *flag;
  const int k0 = blockIdx.x * 64, n0 = blockIdx.y * 64;
  const int tr  = threadIdx.x >> 2;         // 0..63
  const int tc0 = (threadIdx.x & 3) * 16;   // 0,16,32,48
  #pragma unroll
  for (int i = 0; i < 16; i++)
    tile[tr][tc0 + i] = ldg_f(w, (k0 + tr) * 1280 + n0 + tc0 + i, f);
  __syncthreads();
  const int n = n0 + tr;
  float upv[4];
  if (dn){
    #pragma unroll
    for (int r = 0; r < 4; r++) upv[r] = ldg_f(up, r * 1280 + n, f);
  }
  u16 tmp[16];
  #pragma unroll
  for (int i = 0; i < 16; i++){
    int k = k0 + tc0 + i;
    float val = tile[tc0 + i][tr];
    if (dn){
      #pragma unroll
      for (int r = 0; r < 4; r++)
        val += ldg_f(dn, k * 4 + r, f) * upv[r];
    }
    tmp[i] = f2b(val * sc);
  }
  u16* dst = &WT[(rowOff + n) * 1280 + k0 + tc0];
  #pragma unroll
  for (int i = 0; i < 4; i++)
    *(ushort4*)(dst + i * 4) = *(ushort4*)(tmp + i * 4);
}

// ---------- kernel 3a: 128x128 m97-structure GEMM (for N=1280 shapes) ----------
// 640 blocks fill the chip; 256² template would give only 160 blocks here.
template<bool BIAS, bool RESID, bool RAWOUT>
__global__ __launch_bounds__(256) void gemm_bt(
    const u16* __restrict__ A, const u16* __restrict__ BT,
    const void* __restrict__ bias, const void* __restrict__ resid,
    void* __restrict__ Cout, int NOUT, int Kdim, const int* __restrict__ flag)
{
  __shared__ alignas(16) u16 As[128 * 32];
  __shared__ alignas(16) u16 Bs[128 * 32];
  const int tid  = threadIdx.x;
  const int lane = tid & 63;
  const int w    = tid >> 6;
  const int wm   = w >> 1, wn = w & 1;
  const int quad = lane >> 4, l15 = lane & 15;
  const int tileM = blockIdx.y << 7;
  const int tileN = blockIdx.x << 7;
  const int f32 = (BIAS || RESID || RAWOUT) ? *flag : 0;

  f32x4 acc[4][4];
  #pragma unroll
  for (int mi = 0; mi < 4; mi++)
    #pragma unroll
    for (int ni = 0; ni < 4; ni++)
      acc[mi][ni] = (f32x4){0.f, 0.f, 0.f, 0.f};

  for (int k0 = 0; k0 < Kdim; k0 += 32){
    {
      int c = tid;
      gld16(&A [(tileM + (c >> 2)) * Kdim + k0 + ((c & 3) << 3)], (char*)As + c * 16);
      gld16(&BT[(tileN + (c >> 2)) * Kdim + k0 + ((c & 3) << 3)], (char*)Bs + c * 16);
      c = tid + 256;
      gld16(&A [(tileM + (c >> 2)) * Kdim + k0 + ((c & 3) << 3)], (char*)As + c * 16);
      gld16(&BT[(tileN + (c >> 2)) * Kdim + k0 + ((c & 3) << 3)], (char*)Bs + c * 16);
    }
    __syncthreads();

    short8 af[4], bfr[4];
    #pragma unroll
    for (int mi = 0; mi < 4; mi++)
      af[mi] = *(const short8*)(As + (wm * 64 + mi * 16 + l15) * 32 + quad * 8);
    #pragma unroll
    for (int ni = 0; ni < 4; ni++)
      bfr[ni] = *(const short8*)(Bs + (wn * 64 + ni * 16 + l15) * 32 + quad * 8);
    #pragma unroll
    for (int mi = 0; mi < 4; mi++)
      #pragma unroll
      for (int ni = 0; ni < 4; ni++)
        acc[mi][ni] = __builtin_amdgcn_mfma_f32_16x16x32_bf16(
            af[mi], bfr[ni], acc[mi][ni], 0, 0, 0);
    __syncthreads();
  }

  #pragma unroll
  for (int mi = 0; mi < 4; mi++){
    #pragma unroll
    for (int ni = 0; ni < 4; ni++){
      int col = tileN + wn * 64 + ni * 16 + l15;
      float bv = 0.f;
      if (BIAS) bv = ldg_f(bias, col, f32);
      #pragma unroll
      for (int r = 0; r < 4; r++){
        int row = tileM + wm * 64 + mi * 16 + quad * 4 + r;
        float v = acc[mi][ni][r] + bv;
        if (RESID) v += ldg_f(resid, row * NOUT + col, f32);
        if (RAWOUT && f32) ((float*)Cout)[row * NOUT + col] = v;
        else               ((u16*)Cout)[row * NOUT + col]   = f2b(v);
      }
    }
  }
}

// ---------- kernel 3b: 256x256 8-phase MFMA GEMM (QKV projection) ----------
// Schedule per K-tile t: 4 phases {asm ds_read -> barrier -> lgkm(0) ->
// sched_barrier(0) -> 16 MFMA (setprio) -> barrier}; B(t+1) issued at
// phases 1-2, A(t+2) at boundary; boundary wait = vmcnt(4). Never vmcnt(0)
// mid-loop. Fragment reads are INLINE-ASM ds_read_b128 so the compiler
// cannot insert conservative vmcnt drains between gld16 and the reads
// (the T4-defeat this round targets); ordering is guaranteed by our own
// boundary vmcnt+barrier [analyzed race-free] and per-phase lgkmcnt(0).
#define GPHASE(KK, MH)                                                         \
  {                                                                            \
    if ((MH) == 0){                                                            \
      _Pragma("unroll")                                                        \
      for (int n = 0; n < 4; n++){                                             \
        int R = wn * 64 + n * 16 + l15;                                        \
        int sl = (KK) * 4 + quad;                                              \
        bfr[n] = ds_r128(lds_addr(&Bsm[b][R * 64 + ((sl ^ (R & 7)) << 3)]));   \
      }                                                                        \
    }                                                                          \
    short8 af[4];                                                              \
    _Pragma("unroll")                                                          \
    for (int j = 0; j < 4; j++){                                               \
      int R = wm * 128 + ((MH) * 4 + j) * 16 + l15;                            \
      int sl = (KK) * 4 + quad;                                                \
      af[j] = ds_r128(lds_addr(&Asm[b][R * 64 + ((sl ^ (R & 7)) << 3)]));      \
    }                                                                          \
    __builtin_amdgcn_s_barrier();                                              \
    asm volatile("s_waitcnt lgkmcnt(0)" ::: "memory");                         \
    __builtin_amdgcn_sched_barrier(0);                                         \
    __builtin_amdgcn_s_setprio(1);                                             \
    _Pragma("unroll")                                                          \
    for (int j = 0; j < 4; j++)                                                \
      _Pragma("unroll")                                                        \
      for (int n = 0; n < 4; n++)                                              \
        acc[(MH) * 4 + j][n] = __builtin_amdgcn_mfma_f32_16x16x32_bf16(        \
            af[j], bfr[n], acc[(MH) * 4 + j][n], 0, 0, 0);                     \
    __builtin_amdgcn_s_setprio(0);                                             \
    __builtin_amdgcn_s_barrier();                                              \
  }

__global__ __launch_bounds__(512, 2) void gemm256_qkv(
    const u16* __restrict__ A, const u16* __restrict__ BT,
    u16* __restrict__ Cout, u16* __restrict__ vtg,
    int gridX, int Kdim)
{
  __shared__ alignas(16) u16 Asm[2][256 * 64];   // 64 KiB
  __shared__ alignas(16) u16 Bsm[2][256 * 64];   // 64 KiB
  const int tid  = threadIdx.x;
  const int lane = tid & 63;
  const int w    = tid >> 6;
  const int wm   = w >> 2, wn = w & 3;
  const int quad = lane >> 4, l15 = lane & 15;

  // T1: XCD-aware swizzle (grid % 8 == 0)
  const int nwg = gridDim.x;
  const int id  = blockIdx.x;
  const int swz = (id & 7) * (nwg >> 3) + (id >> 3);
  const int bx  = swz % gridX;
  const int by  = swz / gridX;
  const int tileM = by << 8;
  const int tileN = bx << 8;

  // stage one half-tile (1024 chunks of 16B): half 0/1 = A rows 0-127/128-255,
  // half 2/3 = B rows 0-127/128-255.  LDS dest linear (chunk p -> p*16);
  // global source slot = phys_slot ^ (row&7) (inverse swizzle).
  auto stageHalf = [&](int bufi, int half, int kt){
    const int k0 = kt << 6;
    #pragma unroll
    for (int s = 0; s < 2; s++){
      int cl   = s * 512 + tid;                 // 0..1023
      int p    = ((half & 1) << 10) + cl;       // phys chunk in tile (0..2047)
      int row  = p >> 3;
      int lslt = (p & 7) ^ (row & 7);           // logical 16B slot
      if (half < 2)
        gld16(&A [(tileM + row) * Kdim + k0 + lslt * 8], (char*)Asm[bufi] + p * 16);
      else
        gld16(&BT[(tileN + row) * Kdim + k0 + lslt * 8], (char*)Bsm[bufi] + p * 16);
    }
  };

  f32x4 acc[8][4];
  #pragma unroll
  for (int mi = 0; mi < 8; mi++)
    #pragma unroll
    for (int ni = 0; ni < 4; ni++)
      acc[mi][ni] = (f32x4){0.f, 0.f, 0.f, 0.f};

  const int NT = Kdim >> 6;   // 20 K-tiles
  stageHalf(0, 0, 0); stageHalf(0, 1, 0); stageHalf(0, 2, 0); stageHalf(0, 3, 0);
  stageHalf(1, 0, 1); stageHalf(1, 1, 1);
  asm volatile("s_waitcnt vmcnt(4)" ::: "memory");  // tile0 staged; 4 in flight
  __builtin_amdgcn_s_barrier();

  for (int kt = 0; kt < NT; kt++){
    const int b = kt & 1;
    short8 bfr[4];
    if (kt + 1 < NT) stageHalf(b ^ 1, 2, kt + 1);
    GPHASE(0, 0)
    if (kt + 1 < NT) stageHalf(b ^ 1, 3, kt + 1);
    GPHASE(0, 1)
    GPHASE(1, 0)
    GPHASE(1, 1)
    if (kt + 2 < NT){ stageHalf(b, 0, kt + 2); stageHalf(b, 1, kt + 2); }
    if (kt + 1 < NT){
      if (kt + 2 < NT) asm volatile("s_waitcnt vmcnt(4)" ::: "memory");
      else             asm volatile("s_waitcnt vmcnt(0)" ::: "memory");
      __builtin_amdgcn_s_barrier();
    }
  }

  // epilogue: C/D layout col=lane&15, row=quad*4+reg  [m89/m91 verified]
  if (tileN >= 2560){
    #pragma unroll
    for (int mi = 0; mi < 8; mi++){
      #pragma unroll
      for (int ni = 0; ni < 4; ni++){
        int col = tileN + wn * 64 + ni * 16 + l15;
        int hd = col - 2560;
        int hh = hd / 160;
        int dd = hd - hh * 160;
        int row0 = tileM + wm * 128 + mi * 16 + quad * 4;
        int bb = row0 >> 10;
        long addr = ((long)((bb * 8 + hh) * 160 + dd) << 10) | (long)(row0 & 1023);
        ushort4 pk;
        pk.x = f2b(acc[mi][ni][0]); pk.y = f2b(acc[mi][ni][1]);
        pk.z = f2b(acc[mi][ni][2]); pk.w = f2b(acc[mi][ni][3]);
        *(ushort4*)&vtg[addr] = pk;
      }
    }
  } else {
    #pragma unroll
    for (int mi = 0; mi < 8; mi++){
      #pragma unroll
      for (int ni = 0; ni < 4; ni++){
        int col = tileN + wn * 64 + ni * 16 + l15;
        #pragma unroll
        for (int r = 0; r < 4; r++){
          int row = tileM + wm * 128 + mi * 16 + quad * 4 + r;
          Cout[row * 2560 + col] = f2b(acc[mi][ni][r]);
        }
      }
    }
  }
}

// ---------- kernel 4: MFMA flash attention (pipelined) ----------
__global__ __launch_bounds__(256, 2) void attn_mfma(
    const u16* __restrict__ qk, const u16* __restrict__ vtg,
    u16* __restrict__ out)
{
  __shared__ alignas(16) u16 Ks[2 * 64 * 160]; // double-buffered K, stride 160
  __shared__ alignas(16) u16 Vt[160 * 64];     // [d][k] linear, XOR-swizzled data
  __shared__ alignas(16) u16 Ps[4 * 32 * 72];  // per-wave P, pad->72

  const int tid  = threadIdx.x, lane = tid & 63, wv = tid >> 6;
  const int quad = lane >> 4,   l15  = lane & 15;
  const int bh = ((blockIdx.y >> 3) << 3) | blockIdx.x;
  const int qt = blockIdx.y & 7;
  const int b  = bh >> 3, h = bh & 7;
  const int rowBase = (b << 10) + (qt << 7);
  const int kBase   = b << 10;

  short8 qa[2][5];
  #pragma unroll
  for (int mi = 0; mi < 2; mi++)
    #pragma unroll
    for (int kk = 0; kk < 5; kk++)
      qa[mi][kk] = *(const short8*)&qk[
          (rowBase + wv * 32 + mi * 16 + l15) * 2560 + h * 160 + kk * 32 + quad * 8];

  f32x4 o[2][10];
  #pragma unroll
  for (int mi = 0; mi < 2; mi++)
    #pragma unroll
    for (int ni = 0; ni < 10; ni++)
      o[mi][ni] = (f32x4){0.f, 0.f, 0.f, 0.f};
  float mr[2][4], lr[2][4];
  #pragma unroll
  for (int mi = 0; mi < 2; mi++)
    #pragma unroll
    for (int r = 0; r < 4; r++){ mr[mi][r] = -1e30f; lr[mi][r] = 0.f; }

  #pragma unroll
  for (int i = 0; i < 5; i++){
    int c = tid + (i << 8);
    int kr = c / 20, kc = c % 20;
    gld16(&qk[(kBase + kr) * 2560 + 1280 + h * 160 + (kc << 3)],
          (char*)Ks + c * 16);
  }
  __syncthreads();

  int buf = 0;
  for (int kt = 0; kt < 16; kt++){
    #pragma unroll
    for (int i = 0; i < 5; i++){
      int c = tid + (i << 8);
      int d = c >> 3;
      int l = (c & 7) ^ (d & 7);
      gld16(&vtg[((bh * 160 + d) << 10) + (kt << 6) + (l << 3)],
            (char*)Vt + c * 16);
    }
    if (kt < 15){
      #pragma unroll
      for (int i = 0; i < 5; i++){
        int c = tid + (i << 8);
        int kr = c / 20, kc = c % 20;
        gld16(&qk[(kBase + ((kt + 1) << 6) + kr) * 2560 + 1280 + h * 160 + (kc << 3)],
              (char*)Ks + (buf ^ 1) * 20480 + c * 16);
      }
    }
    const u16* KsR = Ks + buf * 10240;

    f32x4 s[2][4];
    #pragma unroll
    for (int mi = 0; mi < 2; mi++)
      #pragma unroll
      for (int ni = 0; ni < 4; ni++)
        s[mi][ni] = (f32x4){0.f, 0.f, 0.f, 0.f};
    __builtin_amdgcn_s_setprio(1);
    #pragma unroll
    for (int kk = 0; kk < 5; kk++){
      #pragma unroll
      for (int ni = 0; ni < 4; ni++){
        short8 bf = *(const short8*)&KsR[(ni * 16 + l15) * 160 + kk * 32 + quad * 8];
        s[0][ni] = __builtin_amdgcn_mfma_f32_16x16x32_bf16(qa[0][kk], bf, s[0][ni], 0, 0, 0);
        s[1][ni] = __builtin_amdgcn_mfma_f32_16x16x32_bf16(qa[1][kk], bf, s[1][ni], 0, 0, 0);
      }
    }
    __builtin_amdgcn_s_setprio(0);

    float al[2][4];
    #pragma unroll
    for (int mi = 0; mi < 2; mi++){
      #pragma unroll
      for (int r = 0; r < 4; r++){
        float mx = fmaxf(fmaxf(s[mi][0][r], s[mi][1][r]),
                         fmaxf(s[mi][2][r], s[mi][3][r]));
        #pragma unroll
        for (int xm = 1; xm < 16; xm <<= 1) mx = fmaxf(mx, __shfl_xor(mx, xm, 64));
        float mn = fmaxf(mr[mi][r], mx);
        float a  = __expf(mr[mi][r] - mn);
        mr[mi][r] = mn; al[mi][r] = a;
        float sum = 0.f;
        #pragma unroll
        for (int ni = 0; ni < 4; ni++){
          float p = __expf(s[mi][ni][r] - mn);
          s[mi][ni][r] = p; sum += p;
        }
        #pragma unroll
        for (int xm = 1; xm < 16; xm <<= 1) sum += __shfl_xor(sum, xm, 64);
        lr[mi][r] = lr[mi][r] * a + sum;
      }
    }
    #pragma unroll
    for (int mi = 0; mi < 2; mi++)
      #pragma unroll
      for (int ni = 0; ni < 4; ni++)
        #pragma unroll
        for (int r = 0; r < 4; r++)
          Ps[wv * 2304 + (mi * 16 + quad * 4 + r) * 72 + ni * 16 + l15] =
              f2b(s[mi][ni][r]);
    #pragma unroll
    for (int mi = 0; mi < 2; mi++)
      #pragma unroll
      for (int ni = 0; ni < 10; ni++)
        #pragma unroll
        for (int r = 0; r < 4; r++)
          o[mi][ni][r] *= al[mi][r];

    if (kt < 15) asm volatile("s_waitcnt vmcnt(5)" ::: "memory");
    else         asm volatile("s_waitcnt vmcnt(0)" ::: "memory");
    __builtin_amdgcn_s_barrier();

    __builtin_amdgcn_s_setprio(1);
    #pragma unroll
    for (int kk2 = 0; kk2 < 2; kk2++){
      short8 pa0 = *(const short8*)&Ps[wv * 2304 + l15 * 72        + kk2 * 32 + quad * 8];
      short8 pa1 = *(const short8*)&Ps[wv * 2304 + (16 + l15) * 72 + kk2 * 32 + quad * 8];
      #pragma unroll
      for (int ni = 0; ni < 10; ni++){
        short8 vf = *(const short8*)&Vt[((ni * 16 + l15) << 6) +
                                        (((((kk2 << 2) | quad)) ^ (l15 & 7)) << 3)];
        o[0][ni] = __builtin_amdgcn_mfma_f32_16x16x32_bf16(pa0, vf, o[0][ni], 0, 0, 0);
        o[1][ni] = __builtin_amdgcn_mfma_f32_16x16x32_bf16(pa1, vf, o[1][ni], 0, 0, 0);
      }
    }
    __builtin_amdgcn_s_setprio(0);

    asm volatile("s_waitcnt vmcnt(0)" ::: "memory");
    __builtin_amdgcn_s_barrier();
    buf ^= 1;
  }

  #pragma unroll
  for (int mi = 0; mi < 2; mi++){
    #pragma unroll
    for (int r = 0; r < 4; r++){
      float inv = 1.0f / lr[mi][r];
      int row = rowBase + wv * 32 + mi * 16 + quad * 4 + r;
      #pragma unroll
      for (int ni = 0; ni < 10; ni++)
        out[row * 1280 + h * 160 + ni * 16 + l15] = f2b(o[mi][ni][r] * inv);
    }
  }
}

// ---------- launcher ----------
extern "C" void kernel_launch(void* const* d_in, const int* in_sizes, int n_in,
                              void* d_out, int out_size, void* d_ws, size_t ws_size,
                              hipStream_t stream)
{
  const void* hid  = d_in[0];
  const void* pose = d_in[1];
  const void* wm   = d_in[2];
  const void* mb   = d_in[3];
  const void* wq   = d_in[4];
  const void* wk   = d_in[5];
  const void* wv   = d_in[6];
  const void* wo   = d_in[7];
  const void* bo   = d_in[8];
  const void* qd   = d_in[9];
  const void* qu   = d_in[10];
  const void* kd   = d_in[11];
  const void* ku   = d_in[12];
  const void* vd   = d_in[13];
  const void* vu   = d_in[14];
  const void* od   = d_in[15];
  const void* ou   = d_in[16];
  (void)in_sizes; (void)n_in; (void)out_size; (void)ws_size;

  // ws layout (u16 elems), total 46,858,240 u16 + 4B flag = 89.4 MiB
  u16* ws   = (u16*)d_ws;
  u16* qk   = ws;                    // 20,971,520  [8192][2560]
  u16* t    = qk;                    // alias: dead before gemm2 writes qk
  u16* x    = qk + 20971520;         // 10,485,760  [8192][1280]
  u16* vtg  = x + 10485760;          // 10,485,760  [64][160][1024]
  u16* Wbuf = vtg + 10485760;        //  4,915,200  [3840][1280] (reused)
  u16* attnout = x;                  // alias: x dead after gemm2
  int* flag = (int*)(Wbuf + 4915200);

  const float qscale = 0.07905694150420949f;  // 160^-0.5 folded into Wq

  detect_dtype<<<1, 64, 0, stream>>>((const u16*)hid, flag);
  make_t<<<5120, 256, 0, stream>>>(hid, pose, t, flag);
  // x = t @ Wm^T' + mb + hid   (128² structure: 640 blocks fill the chip)
  prep_w<<<dim3(20, 20), 256, 0, stream>>>(wm, nullptr, nullptr, Wbuf, 0, 1.0f, flag);
  gemm_bt<true, true, false><<<dim3(10, 64), 256, 0, stream>>>(
      t, Wbuf, mb, hid, x, 1280, 1280, flag);
  // qk | vtg = x @ [Wq*s|Wk|Wv]_eff   (256² 8-phase: 480 blocks, %8==0)
  prep_w<<<dim3(20, 20), 256, 0, stream>>>(wq, qd, qu, Wbuf, 0, qscale, flag);
  prep_w<<<dim3(20, 20), 256, 0, stream>>>(wk, kd, ku, Wbuf, 1280, 1.0f, flag);
  prep_w<<<dim3(20, 20), 256, 0, stream>>>(wv, vd, vu, Wbuf, 2560, 1.0f, flag);
  gemm256_qkv<<<480, 512, 0, stream>>>(x, Wbuf, qk, vtg, 15, 1280);
  // attention
  attn_mfma<<<dim3(8, 64), 256, 0, stream>>>(qk, vtg, attnout);
  // out = attn @ Wo_eff + bo   (128² structure)
  prep_w<<<dim3(20, 20), 256, 0, stream>>>(wo, od, ou, Wbuf, 0, 1.0f, flag);
  gemm_bt<true, false, true><<<dim3(10, 64), 256, 0, stream>>>(
      attnout, Wbuf, bo, nullptr, d_out, 1280, 1280, flag);
}

// Round 5
// 500.061 us; speedup vs baseline: 1.1539x; 1.0181x over previous
//
#include <hip/hip_runtime.h>
#include <stdint.h>

typedef unsigned short u16;
typedef __attribute__((ext_vector_type(8))) short short8;
typedef __attribute__((ext_vector_type(4))) float f32x4;

// ---------- bf16 helpers ----------
__device__ __forceinline__ float b2f(u16 x){
  union { unsigned u; float f; } v; v.u = ((unsigned)x) << 16; return v.f;
}
__device__ __forceinline__ float b2fs(short x){ return b2f((u16)x); }
__device__ __forceinline__ u16 f2b(float f){
  union { float f; unsigned u; } v; v.f = f;
  unsigned u = v.u;
  u += 0x7FFFu + ((u >> 16) & 1u);   // round-to-nearest-even
  return (u16)(u >> 16);
}
// dtype-flexible scalar load from a RAW harness input buffer
__device__ __forceinline__ float ldg_f(const void* p, int i, int f32){
  return f32 ? ((const float*)p)[i] : b2f(((const u16*)p)[i]);
}
// async global->LDS 16B (LDS dest must be wave-uniform base + lane*16)
__device__ __forceinline__ void gld16(const void* g, void* l){
  __builtin_amdgcn_global_load_lds(
      (__attribute__((address_space(1))) void*)(g),
      (__attribute__((address_space(3))) void*)(l), 16, 0, 0);
}
// 32-bit LDS byte offset of a __shared__ object (for inline-asm ds_read)
__device__ __forceinline__ unsigned lds_addr(const void* p){
  return (unsigned)(size_t)(__attribute__((address_space(3))) const void*)p;
}
// inline-asm ds_read_b128: compiler cannot alias-connect this to the
// global_load_lds writes, so it emits NO conservative vmcnt before it.
// Ordering enforced by counted lgkmcnt + sched_barrier(0) [rule #18].
__device__ __forceinline__ short8 ds_r128(unsigned addr){
  short8 r;
  asm volatile("ds_read_b128 %0, %1" : "=v"(r) : "v"(addr));
  return r;
}

// ---------- kernel 0: detect raw input dtype (bf16 vs fp32) ----------
__global__ void detect_dtype(const u16* __restrict__ hid, int* __restrict__ flag){
  if (blockIdx.x == 0){
    int lane = threadIdx.x & 63;
    int plaus = 0;
    for (int i = lane; i < 512; i += 64){
      u16 v = hid[2 * i];
      int e = (v >> 7) & 0xFF;
      if ((e >= 100 && e <= 140) || (v & 0x7FFF) == 0) plaus++;
    }
    #pragma unroll
    for (int xm = 1; xm < 64; xm <<= 1) plaus += __shfl_xor(plaus, xm, 64);
    if (threadIdx.x == 0) *flag = (plaus < 400) ? 1 : 0;
  }
}

// ---------- kernel 1: t = bf16(hidden + pose), 8 elems/thread ----------
__global__ void make_t(const void* __restrict__ hid, const void* __restrict__ pose,
                       u16* __restrict__ t, const int* __restrict__ flag){
  int base = (blockIdx.x * 256 + threadIdx.x) * 8;
  short8 o;
  if (*flag){
    #pragma unroll
    for (int j = 0; j < 2; j++){
      float4 a = *(const float4*)((const float*)hid  + base + j * 4);
      float4 b = *(const float4*)((const float*)pose + base + j * 4);
      o[j * 4 + 0] = (short)f2b(a.x + b.x);
      o[j * 4 + 1] = (short)f2b(a.y + b.y);
      o[j * 4 + 2] = (short)f2b(a.z + b.z);
      o[j * 4 + 3] = (short)f2b(a.w + b.w);
    }
  } else {
    short8 a = *(const short8*)((const u16*)hid  + base);
    short8 b = *(const short8*)((const u16*)pose + base);
    #pragma unroll
    for (int j = 0; j < 8; j++) o[j] = (short)f2b(b2fs(a[j]) + b2fs(b[j]));
  }
  *(short8*)(t + base) = o;
}

// ---------- kernel 2: coalesced transpose + rank-4 LoRA fold ----------
// WT[rowOff+n][k] = sc*(w[k][n] + dn[k][:]·up[:][n]).  64x64 tiles via LDS.
__global__ void prep_w(const void* __restrict__ w, const void* __restrict__ dn,
                       const void* __restrict__ up, u16* __restrict__ WT,
                       int rowOff, float sc, const int* __restrict__ flag)
{
  __shared__ float tile[64][65];            // 65 ≡ 1 mod 32 -> ≤2-way banks
  const int f = *flag;
  const int k0 = blockIdx.x * 64, n0 = blockIdx.y * 64;
  const int tr  = threadIdx.x >> 2;         // 0..63
  const int tc0 = (threadIdx.x & 3) * 16;   // 0,16,32,48
  #pragma unroll
  for (int i = 0; i < 16; i++)
    tile[tr][tc0 + i] = ldg_f(w, (k0 + tr) * 1280 + n0 + tc0 + i, f);
  __syncthreads();
  const int n = n0 + tr;
  float upv[4];
  if (dn){
    #pragma unroll
    for (int r = 0; r < 4; r++) upv[r] = ldg_f(up, r * 1280 + n, f);
  }
  u16 tmp[16];
  #pragma unroll
  for (int i = 0; i < 16; i++){
    int k = k0 + tc0 + i;
    float val = tile[tc0 + i][tr];
    if (dn){
      #pragma unroll
      for (int r = 0; r < 4; r++)
        val += ldg_f(dn, k * 4 + r, f) * upv[r];
    }
    tmp[i] = f2b(val * sc);
  }
  u16* dst = &WT[(rowOff + n) * 1280 + k0 + tc0];
  #pragma unroll
  for (int i = 0; i < 4; i++)
    *(ushort4*)(dst + i * 4) = *(ushort4*)(tmp + i * 4);
}

// ---------- kernel 3a: 128x128 m97-structure GEMM (for N=1280 shapes) ----------
// 640 blocks fill the chip; 256² template would give only 160 blocks here.
template<bool BIAS, bool RESID, bool RAWOUT>
__global__ __launch_bounds__(256) void gemm_bt(
    const u16* __restrict__ A, const u16* __restrict__ BT,
    const void* __restrict__ bias, const void* __restrict__ resid,
    void* __restrict__ Cout, int NOUT, int Kdim, const int* __restrict__ flag)
{
  __shared__ alignas(16) u16 As[128 * 32];
  __shared__ alignas(16) u16 Bs[128 * 32];
  const int tid  = threadIdx.x;
  const int lane = tid & 63;
  const int w    = tid >> 6;
  const int wm   = w >> 1, wn = w & 1;
  const int quad = lane >> 4, l15 = lane & 15;
  const int tileM = blockIdx.y << 7;
  const int tileN = blockIdx.x << 7;
  const int f32 = (BIAS || RESID || RAWOUT) ? *flag : 0;

  f32x4 acc[4][4];
  #pragma unroll
  for (int mi = 0; mi < 4; mi++)
    #pragma unroll
    for (int ni = 0; ni < 4; ni++)
      acc[mi][ni] = (f32x4){0.f, 0.f, 0.f, 0.f};

  for (int k0 = 0; k0 < Kdim; k0 += 32){
    {
      int c = tid;
      gld16(&A [(tileM + (c >> 2)) * Kdim + k0 + ((c & 3) << 3)], (char*)As + c * 16);
      gld16(&BT[(tileN + (c >> 2)) * Kdim + k0 + ((c & 3) << 3)], (char*)Bs + c * 16);
      c = tid + 256;
      gld16(&A [(tileM + (c >> 2)) * Kdim + k0 + ((c & 3) << 3)], (char*)As + c * 16);
      gld16(&BT[(tileN + (c >> 2)) * Kdim + k0 + ((c & 3) << 3)], (char*)Bs + c * 16);
    }
    __syncthreads();

    short8 af[4], bfr[4];
    #pragma unroll
    for (int mi = 0; mi < 4; mi++)
      af[mi] = *(const short8*)(As + (wm * 64 + mi * 16 + l15) * 32 + quad * 8);
    #pragma unroll
    for (int ni = 0; ni < 4; ni++)
      bfr[ni] = *(const short8*)(Bs + (wn * 64 + ni * 16 + l15) * 32 + quad * 8);
    #pragma unroll
    for (int mi = 0; mi < 4; mi++)
      #pragma unroll
      for (int ni = 0; ni < 4; ni++)
        acc[mi][ni] = __builtin_amdgcn_mfma_f32_16x16x32_bf16(
            af[mi], bfr[ni], acc[mi][ni], 0, 0, 0);
    __syncthreads();
  }

  #pragma unroll
  for (int mi = 0; mi < 4; mi++){
    #pragma unroll
    for (int ni = 0; ni < 4; ni++){
      int col = tileN + wn * 64 + ni * 16 + l15;
      float bv = 0.f;
      if (BIAS) bv = ldg_f(bias, col, f32);
      #pragma unroll
      for (int r = 0; r < 4; r++){
        int row = tileM + wm * 64 + mi * 16 + quad * 4 + r;
        float v = acc[mi][ni][r] + bv;
        if (RESID) v += ldg_f(resid, row * NOUT + col, f32);
        if (RAWOUT && f32) ((float*)Cout)[row * NOUT + col] = v;
        else               ((u16*)Cout)[row * NOUT + col]   = f2b(v);
      }
    }
  }
}

// ---------- kernel 3b: 256x256 free-run MFMA GEMM (QKV projection) ----------
// 512 thr = 8 waves (2M x 4N), per-wave 128x64, BK=64, dbuf LDS (128 KiB),
// slot-XOR swizzle (phys_slot = logical_slot ^ (row&7)), both-sides [rule 21].
// R5 change: NO per-phase barriers (buffer immutable for the whole K-tile; the
// 8 lockstep barriers serialized the LDS and MFMA pipes). Waves free-run over
// 4 phases with a per-wave 2-deep ds_read pipeline: issue phase p+1's frags,
// wait counted lgkmcnt (oldest = phase p's reads), MFMA. Frag regs double-
// buffered (aA/aB, bA/bB) so read-issues never overwrite in-flight operands.
// Boundary per K-tile: barrier(read-done) -> issue A(t+2) -> vmcnt(4) ->
// barrier(stage-done). vmcnt(4) leaves A(t+2) in flight, drains A(t+1)+B(t+1).
#define LGKM_SB(N)                                                     \
  asm volatile("s_waitcnt lgkmcnt(" #N ")" ::: "memory");              \
  __builtin_amdgcn_sched_barrier(0);

#define MFMA16(MH, AF, BF)                                             \
  __builtin_amdgcn_s_setprio(1);                                       \
  _Pragma("unroll")                                                    \
  for (int j = 0; j < 4; j++)                                          \
    _Pragma("unroll")                                                  \
    for (int n = 0; n < 4; n++)                                        \
      acc[(MH) * 4 + j][n] = __builtin_amdgcn_mfma_f32_16x16x32_bf16(  \
          AF[j], BF[n], acc[(MH) * 4 + j][n], 0, 0, 0);                \
  __builtin_amdgcn_s_setprio(0);

__global__ __launch_bounds__(512, 2) void gemm256_qkv(
    const u16* __restrict__ A, const u16* __restrict__ BT,
    u16* __restrict__ Cout, u16* __restrict__ vtg,
    int gridX, int Kdim)
{
  __shared__ alignas(16) u16 Asm[2][256 * 64];   // 64 KiB
  __shared__ alignas(16) u16 Bsm[2][256 * 64];   // 64 KiB
  const int tid  = threadIdx.x;
  const int lane = tid & 63;
  const int w    = tid >> 6;
  const int wm   = w >> 2, wn = w & 3;
  const int quad = lane >> 4, l15 = lane & 15;

  // T1: XCD-aware swizzle (grid % 8 == 0)
  const int nwg = gridDim.x;
  const int id  = blockIdx.x;
  const int swz = (id & 7) * (nwg >> 3) + (id >> 3);
  const int bx  = swz % gridX;
  const int by  = swz / gridX;
  const int tileM = by << 8;
  const int tileN = bx << 8;

  // stage one half-tile (1024 chunks of 16B): half 0/1 = A rows 0-127/128-255,
  // half 2/3 = B rows 0-127/128-255.  LDS dest linear (chunk p -> p*16);
  // global source slot = phys_slot ^ (row&7) (inverse swizzle).
  auto stageHalf = [&](int bufi, int half, int kt){
    const int k0 = kt << 6;
    #pragma unroll
    for (int s = 0; s < 2; s++){
      int cl   = s * 512 + tid;                 // 0..1023
      int p    = ((half & 1) << 10) + cl;       // phys chunk in tile (0..2047)
      int row  = p >> 3;
      int lslt = (p & 7) ^ (row & 7);           // logical 16B slot
      if (half < 2)
        gld16(&A [(tileM + row) * Kdim + k0 + lslt * 8], (char*)Asm[bufi] + p * 16);
      else
        gld16(&BT[(tileN + row) * Kdim + k0 + lslt * 8], (char*)Bsm[bufi] + p * 16);
    }
  };

  // fragment read-issue (asm ds_read, swizzled addr; no waits here)
  auto rdA = [&](short8* dst, int bufi, int mh, int kk){
    #pragma unroll
    for (int j = 0; j < 4; j++){
      int R  = wm * 128 + (mh * 4 + j) * 16 + l15;
      int sl = kk * 4 + quad;
      dst[j] = ds_r128(lds_addr(&Asm[bufi][R * 64 + ((sl ^ (R & 7)) << 3)]));
    }
  };
  auto rdB = [&](short8* dst, int bufi, int kk){
    #pragma unroll
    for (int n = 0; n < 4; n++){
      int R  = wn * 64 + n * 16 + l15;
      int sl = kk * 4 + quad;
      dst[n] = ds_r128(lds_addr(&Bsm[bufi][R * 64 + ((sl ^ (R & 7)) << 3)]));
    }
  };

  f32x4 acc[8][4];
  #pragma unroll
  for (int mi = 0; mi < 8; mi++)
    #pragma unroll
    for (int ni = 0; ni < 4; ni++)
      acc[mi][ni] = (f32x4){0.f, 0.f, 0.f, 0.f};

  const int NT = Kdim >> 6;   // 20 K-tiles
  stageHalf(0, 0, 0); stageHalf(0, 1, 0); stageHalf(0, 2, 0); stageHalf(0, 3, 0);
  stageHalf(1, 0, 1); stageHalf(1, 1, 1);
  asm volatile("s_waitcnt vmcnt(4)" ::: "memory");  // tile0 staged; A(1) in flight
  __builtin_amdgcn_s_barrier();

  for (int kt = 0; kt < NT; kt++){
    const int b = kt & 1;
    if (kt + 1 < NT){ stageHalf(b ^ 1, 2, kt + 1); stageHalf(b ^ 1, 3, kt + 1); }

    short8 aA[4], aB[4], bA[4], bB[4];
    rdB(bA, b, 0); rdA(aA, b, 0, 0);   // phase0 frags   (8 outstanding)
    rdA(aB, b, 1, 0);                  // phase1 A-frags (12)
    LGKM_SB(4)                         // phase0 ready
    MFMA16(0, aA, bA)
    rdB(bB, b, 1); rdA(aA, b, 0, 1);   // phase2 frags   (4+8=12)
    LGKM_SB(8)                         // phase1 ready
    MFMA16(1, aB, bA)
    rdA(aB, b, 1, 1);                  // phase3 A-frags (8+4=12)
    LGKM_SB(4)                         // phase2 ready
    MFMA16(0, aA, bB)
    LGKM_SB(0)                         // phase3 ready
    MFMA16(1, aB, bB)

    __builtin_amdgcn_s_barrier();      // read-done: all waves off buf b
    if (kt + 2 < NT){ stageHalf(b, 0, kt + 2); stageHalf(b, 1, kt + 2); }
    if (kt + 1 < NT){
      if (kt + 2 < NT) asm volatile("s_waitcnt vmcnt(4)" ::: "memory");
      else             asm volatile("s_waitcnt vmcnt(0)" ::: "memory");
      __builtin_amdgcn_s_barrier();    // stage-done: buf b^1 fully visible
    }
  }

  // epilogue: C/D layout col=lane&15, row=quad*4+reg  [m89/m91 verified]
  if (tileN >= 2560){
    #pragma unroll
    for (int mi = 0; mi < 8; mi++){
      #pragma unroll
      for (int ni = 0; ni < 4; ni++){
        int col = tileN + wn * 64 + ni * 16 + l15;
        int hd = col - 2560;
        int hh = hd / 160;
        int dd = hd - hh * 160;
        int row0 = tileM + wm * 128 + mi * 16 + quad * 4;
        int bb = row0 >> 10;
        long addr = ((long)((bb * 8 + hh) * 160 + dd) << 10) | (long)(row0 & 1023);
        ushort4 pk;
        pk.x = f2b(acc[mi][ni][0]); pk.y = f2b(acc[mi][ni][1]);
        pk.z = f2b(acc[mi][ni][2]); pk.w = f2b(acc[mi][ni][3]);
        *(ushort4*)&vtg[addr] = pk;
      }
    }
  } else {
    #pragma unroll
    for (int mi = 0; mi < 8; mi++){
      #pragma unroll
      for (int ni = 0; ni < 4; ni++){
        int col = tileN + wn * 64 + ni * 16 + l15;
        #pragma unroll
        for (int r = 0; r < 4; r++){
          int row = tileM + wm * 128 + mi * 16 + quad * 4 + r;
          Cout[row * 2560 + col] = f2b(acc[mi][ni][r]);
        }
      }
    }
  }
}

// ---------- kernel 4: MFMA flash attention (pipelined) ----------
__global__ __launch_bounds__(256, 2) void attn_mfma(
    const u16* __restrict__ qk, const u16* __restrict__ vtg,
    u16* __restrict__ out)
{
  __shared__ alignas(16) u16 Ks[2 * 64 * 160]; // double-buffered K, stride 160
  __shared__ alignas(16) u16 Vt[160 * 64];     // [d][k] linear, XOR-swizzled data
  __shared__ alignas(16) u16 Ps[4 * 32 * 72];  // per-wave P, pad->72

  const int tid  = threadIdx.x, lane = tid & 63, wv = tid >> 6;
  const int quad = lane >> 4,   l15  = lane & 15;
  const int bh = ((blockIdx.y >> 3) << 3) | blockIdx.x;
  const int qt = blockIdx.y & 7;
  const int b  = bh >> 3, h = bh & 7;
  const int rowBase = (b << 10) + (qt << 7);
  const int kBase   = b << 10;

  short8 qa[2][5];
  #pragma unroll
  for (int mi = 0; mi < 2; mi++)
    #pragma unroll
    for (int kk = 0; kk < 5; kk++)
      qa[mi][kk] = *(const short8*)&qk[
          (rowBase + wv * 32 + mi * 16 + l15) * 2560 + h * 160 + kk * 32 + quad * 8];

  f32x4 o[2][10];
  #pragma unroll
  for (int mi = 0; mi < 2; mi++)
    #pragma unroll
    for (int ni = 0; ni < 10; ni++)
      o[mi][ni] = (f32x4){0.f, 0.f, 0.f, 0.f};
  float mr[2][4], lr[2][4];
  #pragma unroll
  for (int mi = 0; mi < 2; mi++)
    #pragma unroll
    for (int r = 0; r < 4; r++){ mr[mi][r] = -1e30f; lr[mi][r] = 0.f; }

  #pragma unroll
  for (int i = 0; i < 5; i++){
    int c = tid + (i << 8);
    int kr = c / 20, kc = c % 20;
    gld16(&qk[(kBase + kr) * 2560 + 1280 + h * 160 + (kc << 3)],
          (char*)Ks + c * 16);
  }
  __syncthreads();

  int buf = 0;
  for (int kt = 0; kt < 16; kt++){
    #pragma unroll
    for (int i = 0; i < 5; i++){
      int c = tid + (i << 8);
      int d = c >> 3;
      int l = (c & 7) ^ (d & 7);
      gld16(&vtg[((bh * 160 + d) << 10) + (kt << 6) + (l << 3)],
            (char*)Vt + c * 16);
    }
    if (kt < 15){
      #pragma unroll
      for (int i = 0; i < 5; i++){
        int c = tid + (i << 8);
        int kr = c / 20, kc = c % 20;
        gld16(&qk[(kBase + ((kt + 1) << 6) + kr) * 2560 + 1280 + h * 160 + (kc << 3)],
              (char*)Ks + (buf ^ 1) * 20480 + c * 16);
      }
    }
    const u16* KsR = Ks + buf * 10240;

    f32x4 s[2][4];
    #pragma unroll
    for (int mi = 0; mi < 2; mi++)
      #pragma unroll
      for (int ni = 0; ni < 4; ni++)
        s[mi][ni] = (f32x4){0.f, 0.f, 0.f, 0.f};
    __builtin_amdgcn_s_setprio(1);
    #pragma unroll
    for (int kk = 0; kk < 5; kk++){
      #pragma unroll
      for (int ni = 0; ni < 4; ni++){
        short8 bf = *(const short8*)&KsR[(ni * 16 + l15) * 160 + kk * 32 + quad * 8];
        s[0][ni] = __builtin_amdgcn_mfma_f32_16x16x32_bf16(qa[0][kk], bf, s[0][ni], 0, 0, 0);
        s[1][ni] = __builtin_amdgcn_mfma_f32_16x16x32_bf16(qa[1][kk], bf, s[1][ni], 0, 0, 0);
      }
    }
    __builtin_amdgcn_s_setprio(0);

    float al[2][4];
    #pragma unroll
    for (int mi = 0; mi < 2; mi++){
      #pragma unroll
      for (int r = 0; r < 4; r++){
        float mx = fmaxf(fmaxf(s[mi][0][r], s[mi][1][r]),
                         fmaxf(s[mi][2][r], s[mi][3][r]));
        #pragma unroll
        for (int xm = 1; xm < 16; xm <<= 1) mx = fmaxf(mx, __shfl_xor(mx, xm, 64));
        float mn = fmaxf(mr[mi][r], mx);
        float a  = __expf(mr[mi][r] - mn);
        mr[mi][r] = mn; al[mi][r] = a;
        float sum = 0.f;
        #pragma unroll
        for (int ni = 0; ni < 4; ni++){
          float p = __expf(s[mi][ni][r] - mn);
          s[mi][ni][r] = p; sum += p;
        }
        #pragma unroll
        for (int xm = 1; xm < 16; xm <<= 1) sum += __shfl_xor(sum, xm, 64);
        lr[mi][r] = lr[mi][r] * a + sum;
      }
    }
    #pragma unroll
    for (int mi = 0; mi < 2; mi++)
      #pragma unroll
      for (int ni = 0; ni < 4; ni++)
        #pragma unroll
        for (int r = 0; r < 4; r++)
          Ps[wv * 2304 + (mi * 16 + quad * 4 + r) * 72 + ni * 16 + l15] =
              f2b(s[mi][ni][r]);
    #pragma unroll
    for (int mi = 0; mi < 2; mi++)
      #pragma unroll
      for (int ni = 0; ni < 10; ni++)
        #pragma unroll
        for (int r = 0; r < 4; r++)
          o[mi][ni][r] *= al[mi][r];

    if (kt < 15) asm volatile("s_waitcnt vmcnt(5)" ::: "memory");
    else         asm volatile("s_waitcnt vmcnt(0)" ::: "memory");
    __builtin_amdgcn_s_barrier();

    __builtin_amdgcn_s_setprio(1);
    #pragma unroll
    for (int kk2 = 0; kk2 < 2; kk2++){
      short8 pa0 = *(const short8*)&Ps[wv * 2304 + l15 * 72        + kk2 * 32 + quad * 8];
      short8 pa1 = *(const short8*)&Ps[wv * 2304 + (16 + l15) * 72 + kk2 * 32 + quad * 8];
      #pragma unroll
      for (int ni = 0; ni < 10; ni++){
        short8 vf = *(const short8*)&Vt[((ni * 16 + l15) << 6) +
                                        (((((kk2 << 2) | quad)) ^ (l15 & 7)) << 3)];
        o[0][ni] = __builtin_amdgcn_mfma_f32_16x16x32_bf16(pa0, vf, o[0][ni], 0, 0, 0);
        o[1][ni] = __builtin_amdgcn_mfma_f32_16x16x32_bf16(pa1, vf, o[1][ni], 0, 0, 0);
      }
    }
    __builtin_amdgcn_s_setprio(0);

    asm volatile("s_waitcnt vmcnt(0)" ::: "memory");
    __builtin_amdgcn_s_barrier();
    buf ^= 1;
  }

  #pragma unroll
  for (int mi = 0; mi < 2; mi++){
    #pragma unroll
    for (int r = 0; r < 4; r++){
      float inv = 1.0f / lr[mi][r];
      int row = rowBase + wv * 32 + mi * 16 + quad * 4 + r;
      #pragma unroll
      for (int ni = 0; ni < 10; ni++)
        out[row * 1280 + h * 160 + ni * 16 + l15] = f2b(o[mi][ni][r] * inv);
    }
  }
}

// ---------- launcher ----------
extern "C" void kernel_launch(void* const* d_in, const int* in_sizes, int n_in,
                              void* d_out, int out_size, void* d_ws, size_t ws_size,
                              hipStream_t stream)
{
  const void* hid  = d_in[0];
  const void* pose = d_in[1];
  const void* wm   = d_in[2];
  const void* mb   = d_in[3];
  const void* wq   = d_in[4];
  const void* wk   = d_in[5];
  const void* wv   = d_in[6];
  const void* wo   = d_in[7];
  const void* bo   = d_in[8];
  const void* qd   = d_in[9];
  const void* qu   = d_in[10];
  const void* kd   = d_in[11];
  const void* ku   = d_in[12];
  const void* vd   = d_in[13];
  const void* vu   = d_in[14];
  const void* od   = d_in[15];
  const void* ou   = d_in[16];
  (void)in_sizes; (void)n_in; (void)out_size; (void)ws_size;

  // ws layout (u16 elems), total 46,858,240 u16 + 4B flag = 89.4 MiB
  u16* ws   = (u16*)d_ws;
  u16* qk   = ws;                    // 20,971,520  [8192][2560]
  u16* t    = qk;                    // alias: dead before gemm2 writes qk
  u16* x    = qk + 20971520;         // 10,485,760  [8192][1280]
  u16* vtg  = x + 10485760;          // 10,485,760  [64][160][1024]
  u16* Wbuf = vtg + 10485760;        //  4,915,200  [3840][1280] (reused)
  u16* attnout = x;                  // alias: x dead after gemm2
  int* flag = (int*)(Wbuf + 4915200);

  const float qscale = 0.07905694150420949f;  // 160^-0.5 folded into Wq

  detect_dtype<<<1, 64, 0, stream>>>((const u16*)hid, flag);
  make_t<<<5120, 256, 0, stream>>>(hid, pose, t, flag);
  // x = t @ Wm^T' + mb + hid   (128² structure: 640 blocks fill the chip)
  prep_w<<<dim3(20, 20), 256, 0, stream>>>(wm, nullptr, nullptr, Wbuf, 0, 1.0f, flag);
  gemm_bt<true, true, false><<<dim3(10, 64), 256, 0, stream>>>(
      t, Wbuf, mb, hid, x, 1280, 1280, flag);
  // qk | vtg = x @ [Wq*s|Wk|Wv]_eff   (256² free-run: 480 blocks, %8==0)
  prep_w<<<dim3(20, 20), 256, 0, stream>>>(wq, qd, qu, Wbuf, 0, qscale, flag);
  prep_w<<<dim3(20, 20), 256, 0, stream>>>(wk, kd, ku, Wbuf, 1280, 1.0f, flag);
  prep_w<<<dim3(20, 20), 256, 0, stream>>>(wv, vd, vu, Wbuf, 2560, 1.0f, flag);
  gemm256_qkv<<<480, 512, 0, stream>>>(x, Wbuf, qk, vtg, 15, 1280);
  // attention
  attn_mfma<<<dim3(8, 64), 256, 0, stream>>>(qk, vtg, attnout);
  // out = attn @ Wo_eff + bo   (128² structure)
  prep_w<<<dim3(20, 20), 256, 0, stream>>>(wo, od, ou, Wbuf, 0, 1.0f, flag);
  gemm_bt<true, false, true><<<dim3(10, 64), 256, 0, stream>>>(
      attnout, Wbuf, bo, nullptr, d_out, 1280, 1280, flag);
}

// Round 6
// 498.865 us; speedup vs baseline: 1.1566x; 1.0024x over previous
//
#include <hip/hip_runtime.h>
#include <stdint.h>

typedef unsigned short u16;
typedef __attribute__((ext_vector_type(8))) short short8;
typedef __attribute__((ext_vector_type(4))) float f32x4;

// ---------- bf16 helpers ----------
__device__ __forceinline__ float b2f(u16 x){
  union { unsigned u; float f; } v; v.u = ((unsigned)x) << 16; return v.f;
}
__device__ __forceinline__ float b2fs(short x){ return b2f((u16)x); }
__device__ __forceinline__ u16 f2b(float f){
  union { float f; unsigned u; } v; v.f = f;
  unsigned u = v.u;
  u += 0x7FFFu + ((u >> 16) & 1u);   // round-to-nearest-even
  return (u16)(u >> 16);
}
// dtype-flexible scalar load from a RAW harness input buffer
__device__ __forceinline__ float ldg_f(const void* p, int i, int f32){
  return f32 ? ((const float*)p)[i] : b2f(((const u16*)p)[i]);
}
// async global->LDS 16B (LDS dest must be wave-uniform base + lane*16)
__device__ __forceinline__ void gld16(const void* g, void* l){
  __builtin_amdgcn_global_load_lds(
      (__attribute__((address_space(1))) void*)(g),
      (__attribute__((address_space(3))) void*)(l), 16, 0, 0);
}
// 32-bit LDS byte offset of a __shared__ object (for inline-asm ds_read)
__device__ __forceinline__ unsigned lds_addr(const void* p){
  return (unsigned)(size_t)(__attribute__((address_space(3))) const void*)p;
}
// inline-asm ds_read_b128 (no compiler-inserted vmcnt drains; ordering via
// counted lgkmcnt + sched_barrier(0) [rule #18])
__device__ __forceinline__ short8 ds_r128(unsigned addr){
  short8 r;
  asm volatile("ds_read_b128 %0, %1" : "=v"(r) : "v"(addr));
  return r;
}

// ---------- kernel 0: detect raw input dtype (bf16 vs fp32) ----------
__global__ void detect_dtype(const u16* __restrict__ hid, int* __restrict__ flag){
  if (blockIdx.x == 0){
    int lane = threadIdx.x & 63;
    int plaus = 0;
    for (int i = lane; i < 512; i += 64){
      u16 v = hid[2 * i];
      int e = (v >> 7) & 0xFF;
      if ((e >= 100 && e <= 140) || (v & 0x7FFF) == 0) plaus++;
    }
    #pragma unroll
    for (int xm = 1; xm < 64; xm <<= 1) plaus += __shfl_xor(plaus, xm, 64);
    if (threadIdx.x == 0) *flag = (plaus < 400) ? 1 : 0;
  }
}

// ---------- kernel 1: t = bf16(hidden + pose), 8 elems/thread ----------
__global__ void make_t(const void* __restrict__ hid, const void* __restrict__ pose,
                       u16* __restrict__ t, const int* __restrict__ flag){
  int base = (blockIdx.x * 256 + threadIdx.x) * 8;
  short8 o;
  if (*flag){
    #pragma unroll
    for (int j = 0; j < 2; j++){
      float4 a = *(const float4*)((const float*)hid  + base + j * 4);
      float4 b = *(const float4*)((const float*)pose + base + j * 4);
      o[j * 4 + 0] = (short)f2b(a.x + b.x);
      o[j * 4 + 1] = (short)f2b(a.y + b.y);
      o[j * 4 + 2] = (short)f2b(a.z + b.z);
      o[j * 4 + 3] = (short)f2b(a.w + b.w);
    }
  } else {
    short8 a = *(const short8*)((const u16*)hid  + base);
    short8 b = *(const short8*)((const u16*)pose + base);
    #pragma unroll
    for (int j = 0; j < 8; j++) o[j] = (short)f2b(b2fs(a[j]) + b2fs(b[j]));
  }
  *(short8*)(t + base) = o;
}

// ---------- kernel 2: coalesced transpose + rank-4 LoRA fold ----------
// WT[rowOff+n][k] = sc*(w[k][n] + dn[k][:]·up[:][n]).  64x64 tiles via LDS.
__device__ __forceinline__ void prep_body(
    const void* w, const void* dn, const void* up, u16* WT,
    int rowOff, float sc, int f, float tile[64][65])
{
  const int k0 = blockIdx.x * 64, n0 = blockIdx.y * 64;
  const int tr  = threadIdx.x >> 2;         // 0..63
  const int tc0 = (threadIdx.x & 3) * 16;   // 0,16,32,48
  #pragma unroll
  for (int i = 0; i < 16; i++)
    tile[tr][tc0 + i] = ldg_f(w, (k0 + tr) * 1280 + n0 + tc0 + i, f);
  __syncthreads();
  const int n = n0 + tr;
  float upv[4];
  if (dn){
    #pragma unroll
    for (int r = 0; r < 4; r++) upv[r] = ldg_f(up, r * 1280 + n, f);
  }
  u16 tmp[16];
  #pragma unroll
  for (int i = 0; i < 16; i++){
    int k = k0 + tc0 + i;
    float val = tile[tc0 + i][tr];
    if (dn){
      #pragma unroll
      for (int r = 0; r < 4; r++)
        val += ldg_f(dn, k * 4 + r, f) * upv[r];
    }
    tmp[i] = f2b(val * sc);
  }
  u16* dst = &WT[(rowOff + n) * 1280 + k0 + tc0];
  #pragma unroll
  for (int i = 0; i < 4; i++)
    *(ushort4*)(dst + i * 4) = *(ushort4*)(tmp + i * 4);
}

__global__ void prep_w(const void* __restrict__ w, const void* __restrict__ dn,
                       const void* __restrict__ up, u16* __restrict__ WT,
                       int rowOff, float sc, const int* __restrict__ flag)
{
  __shared__ float tile[64][65];
  prep_body(w, dn, up, WT, rowOff, sc, *flag, tile);
}

// fused QKV weight prep: blockIdx.z selects {q,k,v}
__global__ void prep_qkv(
    const void* __restrict__ wq, const void* __restrict__ qd, const void* __restrict__ qu,
    const void* __restrict__ wk, const void* __restrict__ kd, const void* __restrict__ ku,
    const void* __restrict__ wv, const void* __restrict__ vd, const void* __restrict__ vu,
    u16* __restrict__ WT, float qscale, const int* __restrict__ flag)
{
  __shared__ float tile[64][65];
  const int z = blockIdx.z;
  const void *w, *dn, *up; int rowOff; float sc;
  if (z == 0){ w = wq; dn = qd; up = qu; rowOff = 0;    sc = qscale; }
  else if (z == 1){ w = wk; dn = kd; up = ku; rowOff = 1280; sc = 1.0f; }
  else { w = wv; dn = vd; up = vu; rowOff = 2560; sc = 1.0f; }
  prep_body(w, dn, up, WT, rowOff, sc, *flag, tile);
}

// ---------- kernel 3a: 128x128 m97-structure GEMM (for N=1280 shapes) ----------
template<bool BIAS, bool RESID, bool RAWOUT>
__global__ __launch_bounds__(256) void gemm_bt(
    const u16* __restrict__ A, const u16* __restrict__ BT,
    const void* __restrict__ bias, const void* __restrict__ resid,
    void* __restrict__ Cout, int NOUT, int Kdim, const int* __restrict__ flag)
{
  __shared__ alignas(16) u16 As[128 * 32];
  __shared__ alignas(16) u16 Bs[128 * 32];
  const int tid  = threadIdx.x;
  const int lane = tid & 63;
  const int w    = tid >> 6;
  const int wm   = w >> 1, wn = w & 1;
  const int quad = lane >> 4, l15 = lane & 15;
  const int tileM = blockIdx.y << 7;
  const int tileN = blockIdx.x << 7;
  const int f32 = (BIAS || RESID || RAWOUT) ? *flag : 0;

  f32x4 acc[4][4];
  #pragma unroll
  for (int mi = 0; mi < 4; mi++)
    #pragma unroll
    for (int ni = 0; ni < 4; ni++)
      acc[mi][ni] = (f32x4){0.f, 0.f, 0.f, 0.f};

  for (int k0 = 0; k0 < Kdim; k0 += 32){
    {
      int c = tid;
      gld16(&A [(tileM + (c >> 2)) * Kdim + k0 + ((c & 3) << 3)], (char*)As + c * 16);
      gld16(&BT[(tileN + (c >> 2)) * Kdim + k0 + ((c & 3) << 3)], (char*)Bs + c * 16);
      c = tid + 256;
      gld16(&A [(tileM + (c >> 2)) * Kdim + k0 + ((c & 3) << 3)], (char*)As + c * 16);
      gld16(&BT[(tileN + (c >> 2)) * Kdim + k0 + ((c & 3) << 3)], (char*)Bs + c * 16);
    }
    __syncthreads();

    short8 af[4], bfr[4];
    #pragma unroll
    for (int mi = 0; mi < 4; mi++)
      af[mi] = *(const short8*)(As + (wm * 64 + mi * 16 + l15) * 32 + quad * 8);
    #pragma unroll
    for (int ni = 0; ni < 4; ni++)
      bfr[ni] = *(const short8*)(Bs + (wn * 64 + ni * 16 + l15) * 32 + quad * 8);
    #pragma unroll
    for (int mi = 0; mi < 4; mi++)
      #pragma unroll
      for (int ni = 0; ni < 4; ni++)
        acc[mi][ni] = __builtin_amdgcn_mfma_f32_16x16x32_bf16(
            af[mi], bfr[ni], acc[mi][ni], 0, 0, 0);
    __syncthreads();
  }

  #pragma unroll
  for (int mi = 0; mi < 4; mi++){
    #pragma unroll
    for (int ni = 0; ni < 4; ni++){
      int col = tileN + wn * 64 + ni * 16 + l15;
      float bv = 0.f;
      if (BIAS) bv = ldg_f(bias, col, f32);
      #pragma unroll
      for (int r = 0; r < 4; r++){
        int row = tileM + wm * 64 + mi * 16 + quad * 4 + r;
        float v = acc[mi][ni][r] + bv;
        if (RESID) v += ldg_f(resid, row * NOUT + col, f32);
        if (RAWOUT && f32) ((float*)Cout)[row * NOUT + col] = v;
        else               ((u16*)Cout)[row * NOUT + col]   = f2b(v);
      }
    }
  }
}

// ---------- kernel 3b: 256x256 MFMA GEMM, hoisted addressing (QKV) ----------
// R6: all K-loop addresses hoisted to base regs + literal offsets.
//  - stage: ONE u32 voff per matrix (+128 B/K-tile); the 4 half/s variants are
//    compile-time consts (+163840/+327680/+491520) since swizzle terms are
//    invariant under 64/128-row steps (p&7, row&7 unchanged).
//  - ds_read: 4 base regs (A/B x kk0/kk1, kk1 = base^64); frag index m -> +m*2048;
//    buffer parity -> +32768 (loop unrolled x2 so it's compile-time).
// Schedule identical to R5 (same accumulate order => same absmax):
//  per K-tile: stage B(t+1) | 12 reads -> lgkm(4) MFMA -> ... -> lgkm(0) MFMA |
//  barrier | stage A(t+2) | vmcnt(4) barrier.  Never vmcnt(0) mid-loop.
#define LGKM_SB(N)                                                     \
  asm volatile("s_waitcnt lgkmcnt(" #N ")" ::: "memory");              \
  __builtin_amdgcn_sched_barrier(0);

#define MFMA16(MH, AF, BF)                                             \
  __builtin_amdgcn_s_setprio(1);                                       \
  _Pragma("unroll")                                                    \
  for (int j = 0; j < 4; j++)                                          \
    _Pragma("unroll")                                                  \
    for (int n = 0; n < 4; n++)                                        \
      acc[(MH) * 4 + j][n] = __builtin_amdgcn_mfma_f32_16x16x32_bf16(  \
          AF[j], BF[n], acc[(MH) * 4 + j][n], 0, 0, 0);                \
  __builtin_amdgcn_s_setprio(0);

#define STAGE_A(BUF, V)                                                         \
  { gld16((const char*)A + (V),           (char*)Asm[BUF] + ldsc);              \
    gld16((const char*)A + (V) + 163840u, (char*)Asm[BUF] + ldsc + 8192);       \
    gld16((const char*)A + (V) + 327680u, (char*)Asm[BUF] + ldsc + 16384);      \
    gld16((const char*)A + (V) + 491520u, (char*)Asm[BUF] + ldsc + 24576); }

#define STAGE_B(BUF, V)                                                         \
  { gld16((const char*)BT + (V),           (char*)Bsm[BUF] + ldsc);             \
    gld16((const char*)BT + (V) + 163840u, (char*)Bsm[BUF] + ldsc + 8192);      \
    gld16((const char*)BT + (V) + 327680u, (char*)Bsm[BUF] + ldsc + 16384);     \
    gld16((const char*)BT + (V) + 491520u, (char*)Bsm[BUF] + ldsc + 24576); }

// one K-tile; BU compile-time buffer parity; STB/STA stage guards; VMC literal
#define KTILE(BU, STB, STA, VMC)                                               \
  {                                                                            \
    const unsigned aR0 = aK0 + (BU) * 32768u, aR1 = aK1 + (BU) * 32768u;       \
    const unsigned bR0 = bK0 + (BU) * 32768u, bR1 = bK1 + (BU) * 32768u;       \
    if (STB){ STAGE_B((BU) ^ 1, voffB) }                                       \
    short8 aA[4], aB[4], bA[4], bB[4];                                         \
    bA[0] = ds_r128(bR0);          bA[1] = ds_r128(bR0 + 2048u);               \
    bA[2] = ds_r128(bR0 + 4096u);  bA[3] = ds_r128(bR0 + 6144u);               \
    aA[0] = ds_r128(aR0);          aA[1] = ds_r128(aR0 + 2048u);               \
    aA[2] = ds_r128(aR0 + 4096u);  aA[3] = ds_r128(aR0 + 6144u);               \
    aB[0] = ds_r128(aR0 + 8192u);  aB[1] = ds_r128(aR0 + 10240u);              \
    aB[2] = ds_r128(aR0 + 12288u); aB[3] = ds_r128(aR0 + 14336u);              \
    LGKM_SB(4)                                                                 \
    MFMA16(0, aA, bA)                                                          \
    bB[0] = ds_r128(bR1);          bB[1] = ds_r128(bR1 + 2048u);               \
    bB[2] = ds_r128(bR1 + 4096u);  bB[3] = ds_r128(bR1 + 6144u);               \
    aA[0] = ds_r128(aR1);          aA[1] = ds_r128(aR1 + 2048u);               \
    aA[2] = ds_r128(aR1 + 4096u);  aA[3] = ds_r128(aR1 + 6144u);               \
    LGKM_SB(8)                                                                 \
    MFMA16(1, aB, bA)                                                          \
    aB[0] = ds_r128(aR1 + 8192u);  aB[1] = ds_r128(aR1 + 10240u);              \
    aB[2] = ds_r128(aR1 + 12288u); aB[3] = ds_r128(aR1 + 14336u);              \
    LGKM_SB(4)                                                                 \
    MFMA16(0, aA, bB)                                                          \
    LGKM_SB(0)                                                                 \
    MFMA16(1, aB, bB)                                                          \
    __builtin_amdgcn_s_barrier();                                              \
    if (STA){ STAGE_A((BU), voffA) }                                           \
    voffA += 128u; voffB += 128u;                                              \
    if (STB){ asm volatile("s_waitcnt vmcnt(" VMC ")" ::: "memory");           \
              __builtin_amdgcn_s_barrier(); }                                  \
  }

__global__ __launch_bounds__(512, 2) void gemm256_qkv(
    const u16* __restrict__ A, const u16* __restrict__ BT,
    u16* __restrict__ Cout, u16* __restrict__ vtg)
{
  __shared__ alignas(16) u16 Asm[2][256 * 64];   // 64 KiB
  __shared__ alignas(16) u16 Bsm[2][256 * 64];   // 64 KiB
  const int tid  = threadIdx.x;
  const int lane = tid & 63;
  const int w    = tid >> 6;
  const int wm   = w >> 2, wn = w & 3;
  const int quad = lane >> 4, l15 = lane & 15;

  // T1: XCD-aware swizzle (480 % 8 == 0)
  const int nwg = gridDim.x;
  const int id  = blockIdx.x;
  const int swz = (id & 7) * (nwg >> 3) + (id >> 3);
  const int bx  = swz % 15;
  const int by  = swz / 15;
  const int tileM = by << 8;
  const int tileN = bx << 8;

  // hoisted stage addressing: chunk p = h*1024 + s*512 + tid
  // row(p) = p>>3, slot = (p&7)^(row&7) -- invariant in h,s => const offsets
  const int prow = tid >> 3;
  const int pslt = (tid & 7) ^ (prow & 7);
  unsigned voffA = (unsigned)(((tileM + prow) * 1280 + pslt * 8) * 2);
  unsigned voffB = (unsigned)(((tileN + prow) * 1280 + pslt * 8) * 2);
  const unsigned ldsc = (unsigned)tid * 16u;

  // hoisted ds_read bases: addr(R,kk) = R*128 + ((kk*4+quad)^(R&7))*16,
  // R&7 == l15&7 for all frags -> kk1 = kk0 ^ 64; frag m -> +m*2048
  const unsigned s0 = (unsigned)((quad ^ (l15 & 7)) << 4);
  const unsigned aK0 = lds_addr(&Asm[0][0]) + (unsigned)((wm * 128 + l15) * 128) + s0;
  const unsigned bK0 = lds_addr(&Bsm[0][0]) + (unsigned)((wn * 64  + l15) * 128) + s0;
  const unsigned aK1 = aK0 ^ 64u;
  const unsigned bK1 = bK0 ^ 64u;

  f32x4 acc[8][4];
  #pragma unroll
  for (int mi = 0; mi < 8; mi++)
    #pragma unroll
    for (int ni = 0; ni < 4; ni++)
      acc[mi][ni] = (f32x4){0.f, 0.f, 0.f, 0.f};

  // prologue: A(0), B(0), A(1); vmcnt(4) -> tile0 staged, A(1) in flight
  STAGE_A(0, voffA) STAGE_B(0, voffB)
  voffA += 128u; voffB += 128u;
  STAGE_A(1, voffA)
  voffA += 128u;
  asm volatile("s_waitcnt vmcnt(4)" ::: "memory");
  __builtin_amdgcn_s_barrier();

  // NT = 20 K-tiles: 9 regular pairs + peeled (t=18, t=19)
  for (int i = 0; i < 9; i++){
    KTILE(0, 1, 1, "4")
    KTILE(1, 1, 1, "4")
  }
  KTILE(0, 1, 0, "0")   // t=18: stage B(19); drain fully for final tile
  KTILE(1, 0, 0, "0")   // t=19: pure compute

  // epilogue: C/D layout col=lane&15, row=quad*4+reg  [m89/m91 verified]
  if (tileN >= 2560){
    #pragma unroll
    for (int mi = 0; mi < 8; mi++){
      #pragma unroll
      for (int ni = 0; ni < 4; ni++){
        int col = tileN + wn * 64 + ni * 16 + l15;
        int hd = col - 2560;
        int hh = hd / 160;
        int dd = hd - hh * 160;
        int row0 = tileM + wm * 128 + mi * 16 + quad * 4;
        int bb = row0 >> 10;
        long addr = ((long)((bb * 8 + hh) * 160 + dd) << 10) | (long)(row0 & 1023);
        ushort4 pk;
        pk.x = f2b(acc[mi][ni][0]); pk.y = f2b(acc[mi][ni][1]);
        pk.z = f2b(acc[mi][ni][2]); pk.w = f2b(acc[mi][ni][3]);
        *(ushort4*)&vtg[addr] = pk;
      }
    }
  } else {
    #pragma unroll
    for (int mi = 0; mi < 8; mi++){
      #pragma unroll
      for (int ni = 0; ni < 4; ni++){
        int col = tileN + wn * 64 + ni * 16 + l15;
        #pragma unroll
        for (int r = 0; r < 4; r++){
          int row = tileM + wm * 128 + mi * 16 + quad * 4 + r;
          Cout[row * 2560 + col] = f2b(acc[mi][ni][r]);
        }
      }
    }
  }
}

// ---------- kernel 4: MFMA flash attention (pipelined) ----------
__global__ __launch_bounds__(256, 2) void attn_mfma(
    const u16* __restrict__ qk, const u16* __restrict__ vtg,
    u16* __restrict__ out)
{
  __shared__ alignas(16) u16 Ks[2 * 64 * 160]; // double-buffered K, stride 160
  __shared__ alignas(16) u16 Vt[160 * 64];     // [d][k] linear, XOR-swizzled data
  __shared__ alignas(16) u16 Ps[4 * 32 * 72];  // per-wave P, pad->72

  const int tid  = threadIdx.x, lane = tid & 63, wv = tid >> 6;
  const int quad = lane >> 4,   l15  = lane & 15;
  const int bh = ((blockIdx.y >> 3) << 3) | blockIdx.x;
  const int qt = blockIdx.y & 7;
  const int b  = bh >> 3, h = bh & 7;
  const int rowBase = (b << 10) + (qt << 7);
  const int kBase   = b << 10;

  short8 qa[2][5];
  #pragma unroll
  for (int mi = 0; mi < 2; mi++)
    #pragma unroll
    for (int kk = 0; kk < 5; kk++)
      qa[mi][kk] = *(const short8*)&qk[
          (rowBase + wv * 32 + mi * 16 + l15) * 2560 + h * 160 + kk * 32 + quad * 8];

  f32x4 o[2][10];
  #pragma unroll
  for (int mi = 0; mi < 2; mi++)
    #pragma unroll
    for (int ni = 0; ni < 10; ni++)
      o[mi][ni] = (f32x4){0.f, 0.f, 0.f, 0.f};
  float mr[2][4], lr[2][4];
  #pragma unroll
  for (int mi = 0; mi < 2; mi++)
    #pragma unroll
    for (int r = 0; r < 4; r++){ mr[mi][r] = -1e30f; lr[mi][r] = 0.f; }

  #pragma unroll
  for (int i = 0; i < 5; i++){
    int c = tid + (i << 8);
    int kr = c / 20, kc = c % 20;
    gld16(&qk[(kBase + kr) * 2560 + 1280 + h * 160 + (kc << 3)],
          (char*)Ks + c * 16);
  }
  __syncthreads();

  int buf = 0;
  for (int kt = 0; kt < 16; kt++){
    #pragma unroll
    for (int i = 0; i < 5; i++){
      int c = tid + (i << 8);
      int d = c >> 3;
      int l = (c & 7) ^ (d & 7);
      gld16(&vtg[((bh * 160 + d) << 10) + (kt << 6) + (l << 3)],
            (char*)Vt + c * 16);
    }
    if (kt < 15){
      #pragma unroll
      for (int i = 0; i < 5; i++){
        int c = tid + (i << 8);
        int kr = c / 20, kc = c % 20;
        gld16(&qk[(kBase + ((kt + 1) << 6) + kr) * 2560 + 1280 + h * 160 + (kc << 3)],
              (char*)Ks + (buf ^ 1) * 20480 + c * 16);
      }
    }
    const u16* KsR = Ks + buf * 10240;

    f32x4 s[2][4];
    #pragma unroll
    for (int mi = 0; mi < 2; mi++)
      #pragma unroll
      for (int ni = 0; ni < 4; ni++)
        s[mi][ni] = (f32x4){0.f, 0.f, 0.f, 0.f};
    __builtin_amdgcn_s_setprio(1);
    #pragma unroll
    for (int kk = 0; kk < 5; kk++){
      #pragma unroll
      for (int ni = 0; ni < 4; ni++){
        short8 bf = *(const short8*)&KsR[(ni * 16 + l15) * 160 + kk * 32 + quad * 8];
        s[0][ni] = __builtin_amdgcn_mfma_f32_16x16x32_bf16(qa[0][kk], bf, s[0][ni], 0, 0, 0);
        s[1][ni] = __builtin_amdgcn_mfma_f32_16x16x32_bf16(qa[1][kk], bf, s[1][ni], 0, 0, 0);
      }
    }
    __builtin_amdgcn_s_setprio(0);

    float al[2][4];
    #pragma unroll
    for (int mi = 0; mi < 2; mi++){
      #pragma unroll
      for (int r = 0; r < 4; r++){
        float mx = fmaxf(fmaxf(s[mi][0][r], s[mi][1][r]),
                         fmaxf(s[mi][2][r], s[mi][3][r]));
        #pragma unroll
        for (int xm = 1; xm < 16; xm <<= 1) mx = fmaxf(mx, __shfl_xor(mx, xm, 64));
        float mn = fmaxf(mr[mi][r], mx);
        float a  = __expf(mr[mi][r] - mn);
        mr[mi][r] = mn; al[mi][r] = a;
        float sum = 0.f;
        #pragma unroll
        for (int ni = 0; ni < 4; ni++){
          float p = __expf(s[mi][ni][r] - mn);
          s[mi][ni][r] = p; sum += p;
        }
        #pragma unroll
        for (int xm = 1; xm < 16; xm <<= 1) sum += __shfl_xor(sum, xm, 64);
        lr[mi][r] = lr[mi][r] * a + sum;
      }
    }
    #pragma unroll
    for (int mi = 0; mi < 2; mi++)
      #pragma unroll
      for (int ni = 0; ni < 4; ni++)
        #pragma unroll
        for (int r = 0; r < 4; r++)
          Ps[wv * 2304 + (mi * 16 + quad * 4 + r) * 72 + ni * 16 + l15] =
              f2b(s[mi][ni][r]);
    #pragma unroll
    for (int mi = 0; mi < 2; mi++)
      #pragma unroll
      for (int ni = 0; ni < 10; ni++)
        #pragma unroll
        for (int r = 0; r < 4; r++)
          o[mi][ni][r] *= al[mi][r];

    if (kt < 15) asm volatile("s_waitcnt vmcnt(5)" ::: "memory");
    else         asm volatile("s_waitcnt vmcnt(0)" ::: "memory");
    __builtin_amdgcn_s_barrier();

    __builtin_amdgcn_s_setprio(1);
    #pragma unroll
    for (int kk2 = 0; kk2 < 2; kk2++){
      short8 pa0 = *(const short8*)&Ps[wv * 2304 + l15 * 72        + kk2 * 32 + quad * 8];
      short8 pa1 = *(const short8*)&Ps[wv * 2304 + (16 + l15) * 72 + kk2 * 32 + quad * 8];
      #pragma unroll
      for (int ni = 0; ni < 10; ni++){
        short8 vf = *(const short8*)&Vt[((ni * 16 + l15) << 6) +
                                        (((((kk2 << 2) | quad)) ^ (l15 & 7)) << 3)];
        o[0][ni] = __builtin_amdgcn_mfma_f32_16x16x32_bf16(pa0, vf, o[0][ni], 0, 0, 0);
        o[1][ni] = __builtin_amdgcn_mfma_f32_16x16x32_bf16(pa1, vf, o[1][ni], 0, 0, 0);
      }
    }
    __builtin_amdgcn_s_setprio(0);

    asm volatile("s_waitcnt vmcnt(0)" ::: "memory");
    __builtin_amdgcn_s_barrier();
    buf ^= 1;
  }

  #pragma unroll
  for (int mi = 0; mi < 2; mi++){
    #pragma unroll
    for (int r = 0; r < 4; r++){
      float inv = 1.0f / lr[mi][r];
      int row = rowBase + wv * 32 + mi * 16 + quad * 4 + r;
      #pragma unroll
      for (int ni = 0; ni < 10; ni++)
        out[row * 1280 + h * 160 + ni * 16 + l15] = f2b(o[mi][ni][r] * inv);
    }
  }
}

// ---------- launcher ----------
extern "C" void kernel_launch(void* const* d_in, const int* in_sizes, int n_in,
                              void* d_out, int out_size, void* d_ws, size_t ws_size,
                              hipStream_t stream)
{
  const void* hid  = d_in[0];
  const void* pose = d_in[1];
  const void* wm   = d_in[2];
  const void* mb   = d_in[3];
  const void* wq   = d_in[4];
  const void* wk   = d_in[5];
  const void* wv   = d_in[6];
  const void* wo   = d_in[7];
  const void* bo   = d_in[8];
  const void* qd   = d_in[9];
  const void* qu   = d_in[10];
  const void* kd   = d_in[11];
  const void* ku   = d_in[12];
  const void* vd   = d_in[13];
  const void* vu   = d_in[14];
  const void* od   = d_in[15];
  const void* ou   = d_in[16];
  (void)in_sizes; (void)n_in; (void)out_size; (void)ws_size;

  // ws layout (u16 elems), total 46,858,240 u16 + 4B flag = 89.4 MiB
  u16* ws   = (u16*)d_ws;
  u16* qk   = ws;                    // 20,971,520  [8192][2560]
  u16* t    = qk;                    // alias: dead before gemm2 writes qk
  u16* x    = qk + 20971520;         // 10,485,760  [8192][1280]
  u16* vtg  = x + 10485760;          // 10,485,760  [64][160][1024]
  u16* Wbuf = vtg + 10485760;        //  4,915,200  [3840][1280] (reused)
  u16* attnout = x;                  // alias: x dead after gemm2
  int* flag = (int*)(Wbuf + 4915200);

  const float qscale = 0.07905694150420949f;  // 160^-0.5 folded into Wq

  detect_dtype<<<1, 64, 0, stream>>>((const u16*)hid, flag);
  make_t<<<5120, 256, 0, stream>>>(hid, pose, t, flag);
  // x = t @ Wm^T' + mb + hid   (128² structure: 640 blocks fill the chip)
  prep_w<<<dim3(20, 20), 256, 0, stream>>>(wm, nullptr, nullptr, Wbuf, 0, 1.0f, flag);
  gemm_bt<true, true, false><<<dim3(10, 64), 256, 0, stream>>>(
      t, Wbuf, mb, hid, x, 1280, 1280, flag);
  // qk | vtg = x @ [Wq*s|Wk|Wv]_eff   (fused prep + 256² hoisted-addr GEMM)
  prep_qkv<<<dim3(20, 20, 3), 256, 0, stream>>>(
      wq, qd, qu, wk, kd, ku, wv, vd, vu, Wbuf, qscale, flag);
  gemm256_qkv<<<480, 512, 0, stream>>>(x, Wbuf, qk, vtg);
  // attention
  attn_mfma<<<dim3(8, 64), 256, 0, stream>>>(qk, vtg, attnout);
  // out = attn @ Wo_eff + bo   (128² structure)
  prep_w<<<dim3(20, 20), 256, 0, stream>>>(wo, od, ou, Wbuf, 0, 1.0f, flag);
  gemm_bt<true, false, true><<<dim3(10, 64), 256, 0, stream>>>(
      attnout, Wbuf, bo, nullptr, d_out, 1280, 1280, flag);
}